// Round 9
// baseline (274.613 us; speedup 1.0000x reference)
//
#include <hip/hip_runtime.h>

#define AS1 __attribute__((address_space(1)))
#define AS3 __attribute__((address_space(3)))

typedef _Float16 f16x8 __attribute__((ext_vector_type(8)));
typedef _Float16 f16x4 __attribute__((ext_vector_type(4)));
typedef _Float16 f16x2 __attribute__((ext_vector_type(2)));
typedef float f32x4 __attribute__((ext_vector_type(4)));

#define MFMA16(a, b, c) __builtin_amdgcn_mfma_f32_16x16x32_f16((a), (b), (c), 0, 0, 0)

// ---------------------------------------------------------------- helpers
__device__ __forceinline__ float silu_f(float v) { return v / (1.f + expf(-v)); }

__device__ __forceinline__ void gload_lds16(const void* g, void* l) {
    __builtin_amdgcn_global_load_lds((AS1 void*)g, (AS3 void*)l, 16, 0, 0);
}

// ---------------------------------------------------------------- fused cvt + proj_ba
// blocks [0,2304): f32->f16 of x|w_qkv|w_gate|w_out, 8 float4/thread (MLP=8).
// Region boundaries are multiples of 2048 float4 -> src uniform per block.
// blocks [2304,3328): beta / log-alpha projections
__global__ __launch_bounds__(256) void cvt_proj(const float* __restrict__ x,
                                                const float* __restrict__ w_qkv,
                                                const float* __restrict__ w_gate,
                                                const float* __restrict__ w_out,
                                                _Float16* __restrict__ dst,
                                                const float* __restrict__ w_beta,
                                                const float* __restrict__ w_alpha,
                                                const float* __restrict__ log_A,
                                                const float* __restrict__ dt_bias,
                                                float* __restrict__ betaB,
                                                float* __restrict__ lalphaB) {
    __shared__ float xs[2048];
    const int bid = blockIdx.x, tid = threadIdx.x;
    if (bid < 2304) {
        long base4 = (long)bid * 2048;   // float4 units
        const float* src; long off4;
        if (base4 < 524288)        { src = x;      off4 = 0; }
        else if (base4 < 2621440)  { src = w_qkv;  off4 = 524288; }
        else if (base4 < 3670016)  { src = w_gate; off4 = 2621440; }
        else                       { src = w_out;  off4 = 3670016; }
        const float4* s4 = (const float4*)src + (base4 - off4) + tid;
        float4 v[8];
#pragma unroll
        for (int i = 0; i < 8; i++) v[i] = s4[i * 256];
        f16x4* d4 = (f16x4*)dst + base4 + tid;
#pragma unroll
        for (int i = 0; i < 8; i++) {
            f16x4 h = { (_Float16)v[i].x, (_Float16)v[i].y,
                        (_Float16)v[i].z, (_Float16)v[i].w };
            d4[i * 256] = h;
        }
        return;
    }
    const int s = bid - 2304;
    *(float4*)&xs[tid * 8]     = *(const float4*)&x[(long)s * 2048 + tid * 8];
    *(float4*)&xs[tid * 8 + 4] = *(const float4*)&x[(long)s * 2048 + tid * 8 + 4];
    __syncthreads();
    const int o = tid >> 3, j = tid & 7;
    const float* w = (o < 16) ? &w_beta[(long)o * 2048] : &w_alpha[(long)(o - 16) * 2048];
    float p = 0.f;
#pragma unroll 4
    for (int i = 0; i < 64; i++) {
        int d = i * 32 + j * 4;
        float4 wv = *(const float4*)&w[d];
        p += xs[d] * wv.x + xs[d + 1] * wv.y + xs[d + 2] * wv.z + xs[d + 3] * wv.w;
    }
    p += __shfl_xor(p, 1); p += __shfl_xor(p, 2); p += __shfl_xor(p, 4);
    if (j == 0) {
        if (o < 16) {
            betaB[s * 16 + o] = 1.f / (1.f + expf(-p));
        } else {
            int h = o - 16;
            float t = p + dt_bias[h];
            float sp = (t > 20.f) ? t : log1pf(expf(t));
            lalphaB[s * 16 + h] = -expf(log_A[h]) * sp;
        }
    }
}

// ---------------------------------------------------------------- GEMM: C(f16) = A * B^T, 128x192 tile
// grid (32,8) = 256 blocks = exactly 1/CU (no tail). 3-buffer LDS pipeline,
// counted vmcnt(5). Per wave per K-step: 24 MFMA : 10 ds_read_b128.
__global__ __launch_bounds__(256) void gemm_bt192(const _Float16* __restrict__ A,
                                                  const _Float16* __restrict__ B,
                                                  _Float16* __restrict__ C, int N, int K) {
    __shared__ _Float16 S[3][320 * 32];   // rows 0..127 A, 128..319 B
    const int tid = threadIdx.x;
    const int rowA0 = blockIdx.y * 128, rowB0 = blockIdx.x * 192;
    const int lane = tid & 63, wv = tid >> 6;
    const int rw = (wv & 1) * 64, cw = (wv >> 1) * 96;
    const int fr = lane & 15, kof = (lane >> 4) * 8, quad = lane >> 4;

    const _Float16* gp[5];
#pragma unroll
    for (int i = 0; i < 5; i++) {
        int idx = tid + 256 * i;
        int row = idx >> 2, c0 = (idx & 3) * 8;
        gp[i] = (row < 128) ? A + (long)(rowA0 + row) * K + c0
                            : B + (long)(rowB0 + row - 128) * K + c0;
    }
    const int NT = K >> 5;

    // prologue: stage tiles 0,1
#pragma unroll
    for (int i = 0; i < 5; i++) gload_lds16(gp[i], &S[0][(tid + 256 * i) * 8]);
#pragma unroll
    for (int i = 0; i < 5; i++) gload_lds16(gp[i] + 32, &S[1][(tid + 256 * i) * 8]);
    asm volatile("s_waitcnt vmcnt(5)" ::: "memory");
    __builtin_amdgcn_s_barrier();

    f32x4 zero = {0.f, 0.f, 0.f, 0.f};
    f32x4 acc[4][6];
#pragma unroll
    for (int mi = 0; mi < 4; mi++)
#pragma unroll
        for (int ni = 0; ni < 6; ni++) acc[mi][ni] = zero;

    int cur = 0;
    for (int t = 0; t < NT; ++t) {
        if (t + 2 < NT) {
            int nb = cur + 2; if (nb >= 3) nb -= 3;
#pragma unroll
            for (int i = 0; i < 5; i++)
                gload_lds16(gp[i] + (t + 2) * 32, &S[nb][(tid + 256 * i) * 8]);
        }
        f16x8 af[4], bf[6];
#pragma unroll
        for (int mi = 0; mi < 4; mi++)
            af[mi] = *(const f16x8*)&S[cur][(rw + mi * 16 + fr) * 32 + kof];
#pragma unroll
        for (int ni = 0; ni < 6; ni++)
            bf[ni] = *(const f16x8*)&S[cur][(128 + cw + ni * 16 + fr) * 32 + kof];
#pragma unroll
        for (int mi = 0; mi < 4; mi++)
#pragma unroll
            for (int ni = 0; ni < 6; ni++)
                acc[mi][ni] = MFMA16(af[mi], bf[ni], acc[mi][ni]);
        if (t + 2 < NT) { asm volatile("s_waitcnt vmcnt(5)" ::: "memory"); }
        else            { asm volatile("s_waitcnt vmcnt(0)" ::: "memory"); }
        __builtin_amdgcn_s_barrier();
        cur = (cur == 2) ? 0 : cur + 1;
    }
    const int rbase = quad * 4;
#pragma unroll
    for (int mi = 0; mi < 4; mi++)
#pragma unroll
        for (int ni = 0; ni < 6; ni++) {
            int row = rowA0 + rw + mi * 16 + rbase;
            int col = rowB0 + cw + ni * 16 + fr;
#pragma unroll
            for (int r = 0; r < 4; r++)
                C[(long)(row + r) * N + col] = (_Float16)acc[mi][ni][r];
        }
}

// ---------------------------------------------------------------- GEMM: C(f32) = A * B^T, 64x64 tile
// Same 3-buffer counted-vmcnt pipeline. Grid (32,16) = 2/CU even.
__global__ __launch_bounds__(256) void gemm_bt6464(const _Float16* __restrict__ A,
                                                   const _Float16* __restrict__ B,
                                                   float* __restrict__ C, int N, int K) {
    __shared__ _Float16 S[3][128 * 32];   // rows 0..63 A, 64..127 B
    const int tid = threadIdx.x;
    const int rowA0 = blockIdx.y * 64, rowB0 = blockIdx.x * 64;
    const int lane = tid & 63, wv = tid >> 6;
    const int rw = (wv & 1) * 32, cwol = (wv >> 1) * 32;
    const int fr = lane & 15, kof = (lane >> 4) * 8, quad = lane >> 4;

    const _Float16* gp[2];
#pragma unroll
    for (int i = 0; i < 2; i++) {
        int idx = tid + 256 * i;
        int row = idx >> 2, c0 = (idx & 3) * 8;
        gp[i] = (row < 64) ? A + (long)(rowA0 + row) * K + c0
                           : B + (long)(rowB0 + row - 64) * K + c0;
    }
    const int NT = K >> 5;

#pragma unroll
    for (int i = 0; i < 2; i++) gload_lds16(gp[i], &S[0][(tid + 256 * i) * 8]);
#pragma unroll
    for (int i = 0; i < 2; i++) gload_lds16(gp[i] + 32, &S[1][(tid + 256 * i) * 8]);
    asm volatile("s_waitcnt vmcnt(2)" ::: "memory");
    __builtin_amdgcn_s_barrier();

    f32x4 zero = {0.f, 0.f, 0.f, 0.f};
    f32x4 acc[2][2];
#pragma unroll
    for (int mi = 0; mi < 2; mi++)
#pragma unroll
        for (int ni = 0; ni < 2; ni++) acc[mi][ni] = zero;

    int cur = 0;
    for (int t = 0; t < NT; ++t) {
        if (t + 2 < NT) {
            int nb = cur + 2; if (nb >= 3) nb -= 3;
#pragma unroll
            for (int i = 0; i < 2; i++)
                gload_lds16(gp[i] + (t + 2) * 32, &S[nb][(tid + 256 * i) * 8]);
        }
        f16x8 af[2], bf[2];
#pragma unroll
        for (int mi = 0; mi < 2; mi++)
            af[mi] = *(const f16x8*)&S[cur][(rw + mi * 16 + fr) * 32 + kof];
#pragma unroll
        for (int ni = 0; ni < 2; ni++)
            bf[ni] = *(const f16x8*)&S[cur][(64 + cwol + ni * 16 + fr) * 32 + kof];
#pragma unroll
        for (int mi = 0; mi < 2; mi++)
#pragma unroll
            for (int ni = 0; ni < 2; ni++)
                acc[mi][ni] = MFMA16(af[mi], bf[ni], acc[mi][ni]);
        if (t + 2 < NT) { asm volatile("s_waitcnt vmcnt(2)" ::: "memory"); }
        else            { asm volatile("s_waitcnt vmcnt(0)" ::: "memory"); }
        __builtin_amdgcn_s_barrier();
        cur = (cur == 2) ? 0 : cur + 1;
    }
    const int rbase = quad * 4;
#pragma unroll
    for (int mi = 0; mi < 2; mi++)
#pragma unroll
        for (int ni = 0; ni < 2; ni++) {
            int row = rowA0 + rw + mi * 16 + rbase;
            int col = rowB0 + cwol + ni * 16 + fr;
#pragma unroll
            for (int r = 0; r < 4; r++)
                C[(long)(row + r) * N + col] = acc[mi][ni][r];
        }
}

// ---------------------------------------------------------------- chunk front: conv+silu+l2norm
// + gamma cumsum + QT/KT/M/T + dual register-resident forward substitution.
__global__ __launch_bounds__(512) void chunk_front(const _Float16* __restrict__ pre,
                                                   const float* __restrict__ cw,
                                                   const float* __restrict__ betaB,
                                                   const float* __restrict__ lalphaB,
                                                   _Float16* __restrict__ Mw,
                                                   _Float16* __restrict__ QTw,
                                                   _Float16* __restrict__ KTw,
                                                   _Float16* __restrict__ WTw,
                                                   _Float16* __restrict__ Bw,
                                                   _Float16* __restrict__ BTw,
                                                   float* __restrict__ gamC) {
    __shared__ _Float16 Kh[64 * 136];
    __shared__ _Float16 Qh[64 * 136];
    __shared__ _Float16 Vh[64 * 136];
    __shared__ _Float16 Tl[64 * 72];
    __shared__ float lg[64], betL[64], bgamL[64], egQ[64], egKr[64];
    const int hc = blockIdx.x, h = hc >> 4, c = hc & 15, hq = h >> 1, s0 = c * 64;
    const int tid = threadIdx.x;

    if (tid < 64) {
        float la = lalphaB[(s0 + tid) * 16 + h];
#pragma unroll
        for (int d = 1; d < 64; d <<= 1) {
            float tv = __shfl_up(la, d, 64);
            if (tid >= d) la += tv;
        }
        lg[tid] = la;
        float la63 = __shfl(la, 63, 64);
        float b = betaB[(s0 + tid) * 16 + h];
        float eg = expf(la);
        betL[tid] = b;
        bgamL[tid] = b * eg;
        egQ[tid] = eg;
        egKr[tid] = expf(la63 - la);
        if (tid == 63) gamC[hc] = eg;
    }

    // ---- causal conv(K=4)+SiLU (+l2 norm for q,k) -> LDS (padded stride 136), f16
    {
        const int tt = tid >> 3, pp = tid & 7, m0 = pp * 16;
        const _Float16* rp[4];
        bool ok0, ok1, ok2;
        {
            int sb = s0 + tt - 3;
            ok0 = (sb >= 0); ok1 = (sb + 1 >= 0); ok2 = (sb + 2 >= 0);
            rp[0] = pre + (long)sb * 6144;
            rp[1] = pre + (long)(sb + 1) * 6144;
            rp[2] = pre + (long)(sb + 2) * 6144;
            rp[3] = pre + (long)(sb + 3) * 6144;
        }
#pragma unroll
        for (int sel = 0; sel < 3; sel++) {
            const int colbase = (sel == 0) ? hq * 128 : (sel == 1) ? 1024 + hq * 128
                                                                   : 2048 + h * 128;
            float vals[16];
            float ss = 0.f;
#pragma unroll
            for (int g = 0; g < 2; g++) {
                const int co = colbase + m0 + g * 8;
                f16x8 r0 = {}, r1 = {}, r2 = {}, r3;
                if (ok0) r0 = *(const f16x8*)&rp[0][co];
                if (ok1) r1 = *(const f16x8*)&rp[1][co];
                if (ok2) r2 = *(const f16x8*)&rp[2][co];
                r3 = *(const f16x8*)&rp[3][co];
#pragma unroll
                for (int j = 0; j < 8; j++) {
                    float4 w = *(const float4*)&cw[(co + j) * 4];
                    float a = (float)r0[j] * w.x + (float)r1[j] * w.y +
                              (float)r2[j] * w.z + (float)r3[j] * w.w;
                    a = silu_f(a);
                    vals[g * 8 + j] = a;
                    ss += a * a;
                }
            }
            float sc = 1.f;
            if (sel < 2) {
                ss += __shfl_xor(ss, 1); ss += __shfl_xor(ss, 2); ss += __shfl_xor(ss, 4);
                sc = rsqrtf(ss + 1e-6f);
                if (sel == 0) sc *= 0.08838834764831843f;  // 1/sqrt(128), queries
            }
            _Float16* dst = (sel == 0) ? Qh : (sel == 1) ? Kh : Vh;
#pragma unroll
            for (int g = 0; g < 2; g++) {
                f16x8 hv;
#pragma unroll
                for (int j = 0; j < 8; j++) hv[j] = (_Float16)(vals[g * 8 + j] * sc);
                *(f16x8*)&dst[tt * 136 + m0 + g * 8] = hv;
            }
        }
    }
    __syncthreads();

    // ---- T (LDS, waves 0-3) and M (global, waves 4-7) via MFMA
    const int wv = tid >> 6, lane = tid & 63;
    const int fr = lane & 15, kof = (lane >> 4) * 8, quad = lane >> 4;
    {
        f32x4 zero = {0.f, 0.f, 0.f, 0.f};
        if (wv < 4) {
            f32x4 accT[4];
#pragma unroll
            for (int ci = 0; ci < 4; ci++) accT[ci] = zero;
            for (int k0 = 0; k0 < 128; k0 += 32) {
                f16x8 ak = *(const f16x8*)&Kh[(wv * 16 + fr) * 136 + k0 + kof];
#pragma unroll
                for (int ci = 0; ci < 4; ci++)
                    accT[ci] = MFMA16(ak, *(const f16x8*)&Kh[(ci * 16 + fr) * 136 + k0 + kof], accT[ci]);
            }
#pragma unroll
            for (int ci = 0; ci < 4; ci++)
#pragma unroll
                for (int r = 0; r < 4; r++) {
                    int t = wv * 16 + quad * 4 + r, i = ci * 16 + fr;
                    float e = expf(lg[t] - lg[i]);
                    Tl[t * 72 + i] = (_Float16)((i < t) ? betL[t] * e * accT[ci][r] : 0.f);
                }
        } else {
            const int w = wv - 4;
            f32x4 accM[4];
#pragma unroll
            for (int ci = 0; ci < 4; ci++) accM[ci] = zero;
            for (int k0 = 0; k0 < 128; k0 += 32) {
                f16x8 aq = *(const f16x8*)&Qh[(w * 16 + fr) * 136 + k0 + kof];
#pragma unroll
                for (int ci = 0; ci < 4; ci++)
                    accM[ci] = MFMA16(aq, *(const f16x8*)&Kh[(ci * 16 + fr) * 136 + k0 + kof], accM[ci]);
            }
#pragma unroll
            for (int ci = 0; ci < 4; ci++)
#pragma unroll
                for (int r = 0; r < 4; r++) {
                    int t = w * 16 + quad * 4 + r, i = ci * 16 + fr;
                    float e = expf(lg[t] - lg[i]);
                    Mw[(long)hc * 4096 + t * 64 + i] = (_Float16)((i <= t) ? e * accM[ci][r] : 0.f);
                }
        }
    }
    __syncthreads();

    // ---- phase 3: register-resident dual forward substitution + QT/KT writes, concurrent
    if (wv < 4) {
        const int jcol = tid & 127;
        const _Float16* Xsrc = (wv < 2) ? Vh : Kh;
        const float* dscale = (wv < 2) ? betL : bgamL;
        float Xs[64];
#pragma unroll
        for (int t = 0; t < 64; t++) Xs[t] = dscale[t] * (float)Xsrc[t * 136 + jcol];
#pragma unroll
        for (int a = 0; a < 4; a++) {
#pragma unroll
            for (int b = 0; b < a; b++) {
#pragma unroll
                for (int r = 0; r < 16; r++) {
                    const _Float16* trow = &Tl[(a * 16 + r) * 72 + b * 16];
                    f16x8 t0 = *(const f16x8*)trow;
                    f16x8 t1 = *(const f16x8*)(trow + 8);
                    float acc = 0.f;
#pragma unroll
                    for (int k = 0; k < 8; k++) acc += (float)t0[k] * Xs[b * 16 + k];
#pragma unroll
                    for (int k = 0; k < 8; k++) acc += (float)t1[k] * Xs[b * 16 + 8 + k];
                    Xs[a * 16 + r] -= acc;
                }
            }
#pragma unroll
            for (int sp = 1; sp < 16; sp++) {
                const _Float16* trow = &Tl[(a * 16 + sp) * 72 + a * 16];
                f16x8 t0 = *(const f16x8*)trow;
                f16x8 t1 = *(const f16x8*)(trow + 8);
                float acc = 0.f;
#pragma unroll
                for (int tp = 0; tp < 16; tp++) {
                    if (tp < sp) acc += (float)(tp < 8 ? t0[tp] : t1[tp - 8]) * Xs[a * 16 + tp];
                }
                Xs[a * 16 + sp] -= acc;
            }
        }
        if (wv < 2) {
#pragma unroll
            for (int v = 0; v < 8; v++) {
                f16x8 hv;
#pragma unroll
                for (int j = 0; j < 8; j++) hv[j] = (_Float16)Xs[v * 8 + j];
                *(f16x8*)&WTw[((long)hc * 128 + jcol) * 64 + v * 8] = hv;
            }
        } else {
#pragma unroll
            for (int t = 0; t < 64; t++) Bw[(long)hc * 8192 + t * 128 + jcol] = (_Float16)Xs[t];
#pragma unroll
            for (int v = 0; v < 8; v++) {
                f16x8 hv;
#pragma unroll
                for (int j = 0; j < 8; j++) hv[j] = (_Float16)Xs[v * 8 + j];
                *(f16x8*)&BTw[((long)hc * 128 + jcol) * 64 + v * 8] = hv;
            }
        }
    } else {
        const int w = wv - 4;
        // QT: rows w*16..w*16+15, scaled by egQ[t]
#pragma unroll
        for (int cp = 0; cp < 4; cp++) {
            int t = w * 16 + fr;
            int cc = cp * 32 + kof;
            f16x8 q = *(const f16x8*)&Qh[t * 136 + cc];
            float s = egQ[t];
            f16x8 o;
#pragma unroll
            for (int j = 0; j < 8; j++) o[j] = (_Float16)(s * (float)q[j]);
            *(f16x8*)&QTw[(long)hc * 8192 + t * 128 + cc] = o;
        }
        // KT: transposed Kh scaled by egKr[t]
        const int m = w * 32 + (lane & 31);
        const int tb = (lane >> 5) * 8;
#pragma unroll
        for (int tp = 0; tp < 4; tp++) {
            int t0 = tb + tp * 16;
            f16x8 o;
#pragma unroll
            for (int j = 0; j < 8; j++)
                o[j] = (_Float16)(egKr[t0 + j] * (float)Kh[(t0 + j) * 136 + m]);
            *(f16x8*)&KTw[(long)hc * 8192 + m * 64 + t0] = o;
        }
    }
}

// ---------------------------------------------------------------- G = K~^T B (f16), Rt = (K~^T W)^T (f32)
__global__ __launch_bounds__(256) void gr_kernel(const _Float16* __restrict__ KTw,
                                                 const _Float16* __restrict__ BTw,
                                                 const _Float16* __restrict__ WTw,
                                                 _Float16* __restrict__ Gw,
                                                 float* __restrict__ Rtw) {
    __shared__ _Float16 KTl[128 * 72], BTl[128 * 72], WTl[128 * 72];
    const long hc = blockIdx.x;
    const int tid = threadIdx.x;
    {
        int r = tid >> 1, c0 = (tid & 1) * 32;
        const _Float16* k_ = &KTw[hc * 8192 + r * 64 + c0];
        const _Float16* b_ = &BTw[hc * 8192 + r * 64 + c0];
        const _Float16* w_ = &WTw[hc * 8192 + r * 64 + c0];
#pragma unroll
        for (int i = 0; i < 4; i++) {
            *(f16x8*)&KTl[r * 72 + c0 + i * 8] = *(const f16x8*)&k_[i * 8];
            *(f16x8*)&BTl[r * 72 + c0 + i * 8] = *(const f16x8*)&b_[i * 8];
            *(f16x8*)&WTl[r * 72 + c0 + i * 8] = *(const f16x8*)&w_[i * 8];
        }
    }
    __syncthreads();
    const int wv = tid >> 6, lane = tid & 63;
    const int fr = lane & 15, kof = (lane >> 4) * 8, quad = lane >> 4;
    f32x4 zero = {0.f, 0.f, 0.f, 0.f};
#pragma unroll
    for (int mi = 0; mi < 2; mi++) {
        int m0 = (wv * 2 + mi) * 16;
        f16x8 a0 = *(const f16x8*)&KTl[(m0 + fr) * 72 + kof];
        f16x8 a1 = *(const f16x8*)&KTl[(m0 + fr) * 72 + 32 + kof];
#pragma unroll
        for (int nj = 0; nj < 8; nj++) {
            f32x4 acc = zero;
            acc = MFMA16(a0, *(const f16x8*)&BTl[(nj * 16 + fr) * 72 + kof], acc);
            acc = MFMA16(a1, *(const f16x8*)&BTl[(nj * 16 + fr) * 72 + 32 + kof], acc);
#pragma unroll
            for (int r = 0; r < 4; r++)
                Gw[hc * 16384 + (long)(m0 + quad * 4 + r) * 128 + nj * 16 + fr] = (_Float16)acc[r];
        }
    }
#pragma unroll
    for (int ji = 0; ji < 2; ji++) {
        int j0 = (wv * 2 + ji) * 16;
        f16x8 a0 = *(const f16x8*)&WTl[(j0 + fr) * 72 + kof];
        f16x8 a1 = *(const f16x8*)&WTl[(j0 + fr) * 72 + 32 + kof];
#pragma unroll
        for (int nm = 0; nm < 8; nm++) {
            f32x4 acc = zero;
            acc = MFMA16(a0, *(const f16x8*)&KTl[(nm * 16 + fr) * 72 + kof], acc);
            acc = MFMA16(a1, *(const f16x8*)&KTl[(nm * 16 + fr) * 72 + 32 + kof], acc);
#pragma unroll
            for (int r = 0; r < 4; r++)
                Rtw[hc * 16384 + (long)(j0 + quad * 4 + r) * 128 + nm * 16 + fr] = acc[r];
        }
    }
}

// ---------------------------------------------------------------- serial affine state scan
__global__ __launch_bounds__(256) void serial_scan(const _Float16* __restrict__ Gw,
                                                   const float* __restrict__ Rtw,
                                                   const float* __restrict__ gamC,
                                                   float* __restrict__ Zdump) {
    __shared__ _Float16 Zhi[32 * 136], Zlo[32 * 136];
    __shared__ _Float16 Gl[128 * 136];
    const int tid = threadIdx.x;
    const int h = blockIdx.x >> 2, js = (blockIdx.x & 3) * 32;
    const int wv = tid >> 6, lane = tid & 63;
    const int fr = lane & 15, kof = (lane >> 4) * 8, quad = lane >> 4;
    const int gr_ = tid >> 1, gc_ = (tid & 1) * 64;

    for (int e = tid; e < 32 * 136; e += 256) { Zhi[e] = (_Float16)0.f; Zlo[e] = (_Float16)0.f; }
    float z[2][2][4];
#pragma unroll
    for (int jt = 0; jt < 2; jt++)
#pragma unroll
        for (int u = 0; u < 2; u++)
#pragma unroll
            for (int r = 0; r < 4; r++) z[jt][u][r] = 0.f;

    long hc0 = (long)h * 16;
    f16x8 gpre[8];
#pragma unroll
    for (int i = 0; i < 8; i++)
        gpre[i] = *(const f16x8*)&Gw[hc0 * 16384 + (long)gr_ * 128 + gc_ + i * 8];
    float rpre[2][2][4];
#pragma unroll
    for (int jt = 0; jt < 2; jt++)
#pragma unroll
        for (int u = 0; u < 2; u++)
#pragma unroll
            for (int r = 0; r < 4; r++)
                rpre[jt][u][r] = Rtw[hc0 * 16384 +
                                     (long)(js + jt * 16 + quad * 4 + r) * 128 +
                                     (2 * wv + u) * 16 + fr];
    __syncthreads();

    for (int c = 0; c < 16; ++c) {
        long hc = (long)h * 16 + c;
        float gC = gamC[hc];
#pragma unroll
        for (int i = 0; i < 8; i++)
            *(f16x8*)&Gl[gr_ * 136 + gc_ + i * 8] = gpre[i];
        long hcn = (long)h * 16 + (c < 15 ? c + 1 : 15);
        f16x8 gnext[8];
#pragma unroll
        for (int i = 0; i < 8; i++)
            gnext[i] = *(const f16x8*)&Gw[hcn * 16384 + (long)gr_ * 128 + gc_ + i * 8];
        float rnext[2][2][4];
#pragma unroll
        for (int jt = 0; jt < 2; jt++)
#pragma unroll
            for (int u = 0; u < 2; u++)
#pragma unroll
                for (int r = 0; r < 4; r++)
                    rnext[jt][u][r] = Rtw[hcn * 16384 +
                                          (long)(js + jt * 16 + quad * 4 + r) * 128 +
                                          (2 * wv + u) * 16 + fr];
        __syncthreads();
        f32x4 acc[2][2];
        f32x4 zero = {0.f, 0.f, 0.f, 0.f};
#pragma unroll
        for (int jt = 0; jt < 2; jt++)
#pragma unroll
            for (int u = 0; u < 2; u++) acc[jt][u] = zero;
        for (int k0 = 0; k0 < 128; k0 += 32) {
            f16x8 ahi[2], alo[2], bfr[2];
#pragma unroll
            for (int jt = 0; jt < 2; jt++) {
                ahi[jt] = *(const f16x8*)&Zhi[(jt * 16 + fr) * 136 + k0 + kof];
                alo[jt] = *(const f16x8*)&Zlo[(jt * 16 + fr) * 136 + k0 + kof];
            }
#pragma unroll
            for (int u = 0; u < 2; u++)
                bfr[u] = *(const f16x8*)&Gl[((2 * wv + u) * 16 + fr) * 136 + k0 + kof];
#pragma unroll
            for (int jt = 0; jt < 2; jt++)
#pragma unroll
                for (int u = 0; u < 2; u++) {
                    acc[jt][u] = MFMA16(ahi[jt], bfr[u], acc[jt][u]);
                    acc[jt][u] = MFMA16(alo[jt], bfr[u], acc[jt][u]);
                }
        }
        __syncthreads();
#pragma unroll
        for (int jt = 0; jt < 2; jt++)
#pragma unroll
            for (int u = 0; u < 2; u++)
#pragma unroll
                for (int r = 0; r < 4; r++) {
                    int j = jt * 16 + quad * 4 + r;
                    int m = (2 * wv + u) * 16 + fr;
                    Zdump[hc * 16384 + (long)(js + j) * 128 + m] = z[jt][u][r];
                    float zn = gC * z[jt][u][r] - acc[jt][u][r] + rpre[jt][u][r];
                    z[jt][u][r] = zn;
                    _Float16 hi = (_Float16)zn;
                    Zhi[j * 136 + m] = hi;
                    Zlo[j * 136 + m] = (_Float16)(zn - (float)hi);
                }
#pragma unroll
        for (int i = 0; i < 8; i++) gpre[i] = gnext[i];
#pragma unroll
        for (int jt = 0; jt < 2; jt++)
#pragma unroll
            for (int u = 0; u < 2; u++)
#pragma unroll
                for (int r = 0; r < 4; r++) rpre[jt][u][r] = rnext[jt][u][r];
    }
}

// ---------------------------------------------------------------- per-chunk output + RMS + gate, fused
// One block per hc, 512 threads (8 waves). Waves 0-3: column-half 0; waves 4-7: half 1.
__global__ __launch_bounds__(512) void out_fused(const float* __restrict__ Zdump,
                                                 const _Float16* __restrict__ Bw,
                                                 const _Float16* __restrict__ WTw,
                                                 const _Float16* __restrict__ QTw,
                                                 const _Float16* __restrict__ Mw,
                                                 const _Float16* __restrict__ pre,
                                                 const float* __restrict__ rms_w,
                                                 _Float16* __restrict__ y) {
    __shared__ _Float16 SThi[128 * 136], STlo[128 * 136];
    __shared__ _Float16 Bl[64 * 136];
    __shared__ _Float16 UT[2][64 * 72];
    __shared__ float rowsq[2][64];
    const long hc = blockIdx.x;
    const int h = (int)(hc >> 4), c = (int)(hc & 15), s0 = c * 64;
    const int tid = threadIdx.x, wv = tid >> 6, lane = tid & 63;
    const int half = wv >> 2, wvh = wv & 3, jh = half * 64;
    const int fr = lane & 15, kof = (lane >> 4) * 8, quad = lane >> 4;
    {
        int r = tid >> 2, c0 = (tid & 3) * 32;        // r: 0..127 dv rows
        const float* src = &Zdump[hc * 16384 + (long)r * 128 + c0];
#pragma unroll
        for (int i = 0; i < 8; i++) {
            float4 v = *(const float4*)&src[i * 4];
            _Float16 h0 = (_Float16)v.x, h1 = (_Float16)v.y, h2 = (_Float16)v.z, h3 = (_Float16)v.w;
            f16x4 hi = {h0, h1, h2, h3};
            f16x4 lo = {(_Float16)(v.x - (float)h0), (_Float16)(v.y - (float)h1),
                        (_Float16)(v.z - (float)h2), (_Float16)(v.w - (float)h3)};
            *(f16x4*)&SThi[r * 136 + c0 + i * 4] = hi;
            *(f16x4*)&STlo[r * 136 + c0 + i * 4] = lo;
        }
        if (tid < 256) {
            int r2 = tid >> 2, cb = (tid & 3) * 32;
            const _Float16* bsrc = &Bw[hc * 8192 + r2 * 128 + cb];
#pragma unroll
            for (int i = 0; i < 4; i++)
                *(f16x8*)&Bl[r2 * 136 + cb + i * 8] = *(const f16x8*)&bsrc[i * 8];
        }
    }
    __syncthreads();
    const int t0 = wvh * 16;
    f16x8 ba[4];
#pragma unroll
    for (int k = 0; k < 4; k++)
        ba[k] = *(const f16x8*)&Bl[(t0 + fr) * 136 + k * 32 + kof];
#pragma unroll
    for (int jt = 0; jt < 4; jt++) {
        f32x4 acc = {0.f, 0.f, 0.f, 0.f};
#pragma unroll
        for (int k = 0; k < 4; k++) {
            acc = MFMA16(ba[k], *(const f16x8*)&SThi[(jh + jt * 16 + fr) * 136 + k * 32 + kof], acc);
            acc = MFMA16(ba[k], *(const f16x8*)&STlo[(jh + jt * 16 + fr) * 136 + k * 32 + kof], acc);
        }
#pragma unroll
        for (int r = 0; r < 4; r++) {
            int t = t0 + quad * 4 + r;
            int j = jt * 16 + fr;
            float w = (float)WTw[hc * 8192 + (long)(jh + j) * 64 + t];
            UT[half][j * 72 + t] = (_Float16)(w - acc[r]);
        }
    }
    __syncthreads();
    f16x8 qa[4], ma[2];
#pragma unroll
    for (int k = 0; k < 4; k++)
        qa[k] = *(const f16x8*)&QTw[hc * 8192 + (long)(t0 + fr) * 128 + k * 32 + kof];
#pragma unroll
    for (int k = 0; k < 2; k++)
        ma[k] = *(const f16x8*)&Mw[hc * 4096 + (long)(t0 + fr) * 64 + k * 32 + kof];
    f32x4 out[4];
#pragma unroll
    for (int jt = 0; jt < 4; jt++) {
        f32x4 acc = {0.f, 0.f, 0.f, 0.f};
#pragma unroll
        for (int k = 0; k < 4; k++) {
            acc = MFMA16(qa[k], *(const f16x8*)&SThi[(jh + jt * 16 + fr) * 136 + k * 32 + kof], acc);
            acc = MFMA16(qa[k], *(const f16x8*)&STlo[(jh + jt * 16 + fr) * 136 + k * 32 + kof], acc);
        }
#pragma unroll
        for (int k = 0; k < 2; k++)
            acc = MFMA16(ma[k], *(const f16x8*)&UT[half][(jt * 16 + fr) * 72 + k * 32 + kof], acc);
        out[jt] = acc;
    }
    // ---- cross-half row RMS: partial sumsq over this half's 4 cols, reduce over fr
    float pr[4];
#pragma unroll
    for (int r = 0; r < 4; r++) {
        float s = 0.f;
#pragma unroll
        for (int jt = 0; jt < 4; jt++) s += out[jt][r] * out[jt][r];
        s += __shfl_xor(s, 1); s += __shfl_xor(s, 2);
        s += __shfl_xor(s, 4); s += __shfl_xor(s, 8);
        pr[r] = s;
    }
    if (fr == 0) {
#pragma unroll
        for (int r = 0; r < 4; r++) rowsq[half][t0 + quad * 4 + r] = pr[r];
    }
    __syncthreads();
#pragma unroll
    for (int r = 0; r < 4; r++) {
        int t = t0 + quad * 4 + r;
        float ss = rowsq[0][t] + rowsq[1][t];
        float sc = rsqrtf(ss * (1.f / 128.f) + 1e-6f);
        long rb = (long)(s0 + t) * 6144 + 4096 + h * 128 + jh;
        long yb_ = (long)(s0 + t) * 2048 + h * 128 + jh;
#pragma unroll
        for (int jt = 0; jt < 4; jt++) {
            int j = jt * 16 + fr;
            float g = silu_f((float)pre[rb + j]);
            y[yb_ + j] = (_Float16)(out[jt][r] * sc * rms_w[jh + j] * g);
        }
    }
}

// ---------------------------------------------------------------- launch
extern "C" void kernel_launch(void* const* d_in, const int* in_sizes, int n_in,
                              void* d_out, int out_size, void* d_ws, size_t ws_size,
                              hipStream_t stream) {
    const float* x       = (const float*)d_in[0];
    const float* w_qkv   = (const float*)d_in[1];
    const float* w_gate  = (const float*)d_in[2];
    const float* w_beta  = (const float*)d_in[3];
    const float* w_alpha = (const float*)d_in[4];
    const float* log_A   = (const float*)d_in[5];
    const float* dt_bias = (const float*)d_in[6];
    const float* conv_w  = (const float*)d_in[7];
    const float* rms_w   = (const float*)d_in[8];
    const float* w_out   = (const float*)d_in[9];
    float* outp = (float*)d_out;

    char* ws = (char*)d_ws;
    size_t off = 0;
    _Float16* xb     = (_Float16*)(ws + off); off += (size_t)1024 * 2048 * 2;   // | contiguous
    _Float16* wfused = (_Float16*)(ws + off); off += (size_t)6144 * 2048 * 2;   // | f16 cvt
    _Float16* woutb  = (_Float16*)(ws + off); off += (size_t)2048 * 2048 * 2;   // | region
    _Float16* yb     = (_Float16*)(ws + off); off += (size_t)1024 * 2048 * 2;
    _Float16* pre    = (_Float16*)(ws + off); off += (size_t)1024 * 6144 * 2;
    float* betaB     = (float*)(ws + off);    off += (size_t)1024 * 16 * 4;
    float* lalphaB   = (float*)(ws + off);    off += (size_t)1024 * 16 * 4;
    _Float16* Mw     = (_Float16*)(ws + off); off += (size_t)256 * 4096 * 2;
    _Float16* QTw    = (_Float16*)(ws + off); off += (size_t)256 * 8192 * 2;
    _Float16* KTw    = (_Float16*)(ws + off); off += (size_t)256 * 8192 * 2;
    _Float16* WTw    = (_Float16*)(ws + off); off += (size_t)256 * 8192 * 2;
    _Float16* Bw     = (_Float16*)(ws + off); off += (size_t)256 * 8192 * 2;
    _Float16* BTw    = (_Float16*)(ws + off); off += (size_t)256 * 8192 * 2;
    float* gamC      = (float*)(ws + off);    off += (size_t)256 * 4;
    _Float16* Gw     = (_Float16*)(ws + off); off += (size_t)256 * 16384 * 2;
    float* Rtw       = (float*)(ws + off);    off += (size_t)256 * 16384 * 4;
    float* Zdump     = (float*)(ws + off);    off += (size_t)256 * 16384 * 4;

    // all f32->f16 conversions (8 float4/thread) + beta/alpha projections, one launch
    cvt_proj<<<3328, 256, 0, stream>>>(x, w_qkv, w_gate, w_out, xb,
                                       w_beta, w_alpha, log_A, dt_bias, betaB, lalphaB);

    // fused qkv+gate projection: 128x192 tiles -> 256 blocks = 1/CU exact, pipelined
    gemm_bt192<<<dim3(32, 8), 256, 0, stream>>>(xb, wfused, pre, 6144, 2048);

    // conv+norm+prep+solve fused: one block per (head,chunk), 8 waves
    chunk_front<<<256, 512, 0, stream>>>(pre, conv_w, betaB, lalphaB,
                                         Mw, QTw, KTw, WTw, Bw, BTw, gamC);
    gr_kernel<<<256, 256, 0, stream>>>(KTw, BTw, WTw, Gw, Rtw);
    serial_scan<<<64, 256, 0, stream>>>(Gw, Rtw, gamC, Zdump);

    // per-chunk output + RMS + gate fused: one block per hc, 8 waves
    out_fused<<<256, 512, 0, stream>>>(Zdump, Bw, WTw, QTw, Mw, pre, rms_w, yb);

    // out projection: 64x64 tiles, pipelined
    gemm_bt6464<<<dim3(32, 16), 256, 0, stream>>>(yb, woutb, outp, 2048, 2048);
}

// Round 10
// 272.611 us; speedup vs baseline: 1.0073x; 1.0073x over previous
//
#include <hip/hip_runtime.h>

#define AS1 __attribute__((address_space(1)))
#define AS3 __attribute__((address_space(3)))

typedef _Float16 f16x8 __attribute__((ext_vector_type(8)));
typedef _Float16 f16x4 __attribute__((ext_vector_type(4)));
typedef _Float16 f16x2 __attribute__((ext_vector_type(2)));
typedef float f32x4 __attribute__((ext_vector_type(4)));

#define MFMA16(a, b, c) __builtin_amdgcn_mfma_f32_16x16x32_f16((a), (b), (c), 0, 0, 0)

// ---------------------------------------------------------------- helpers
__device__ __forceinline__ float silu_f(float v) { return v / (1.f + expf(-v)); }

__device__ __forceinline__ void gload_lds16(const void* g, void* l) {
    __builtin_amdgcn_global_load_lds((AS1 void*)g, (AS3 void*)l, 16, 0, 0);
}

// ---------------------------------------------------------------- fused cvt + proj_ba
// blocks [0,2304): f32->f16 of x|w_qkv|w_gate|w_out, 8 float4/thread (MLP=8).
// blocks [2304,3328): beta / log-alpha projections
__global__ __launch_bounds__(256) void cvt_proj(const float* __restrict__ x,
                                                const float* __restrict__ w_qkv,
                                                const float* __restrict__ w_gate,
                                                const float* __restrict__ w_out,
                                                _Float16* __restrict__ dst,
                                                const float* __restrict__ w_beta,
                                                const float* __restrict__ w_alpha,
                                                const float* __restrict__ log_A,
                                                const float* __restrict__ dt_bias,
                                                float* __restrict__ betaB,
                                                float* __restrict__ lalphaB) {
    __shared__ float xs[2048];
    const int bid = blockIdx.x, tid = threadIdx.x;
    if (bid < 2304) {
        long base4 = (long)bid * 2048;   // float4 units
        const float* src; long off4;
        if (base4 < 524288)        { src = x;      off4 = 0; }
        else if (base4 < 2621440)  { src = w_qkv;  off4 = 524288; }
        else if (base4 < 3670016)  { src = w_gate; off4 = 2621440; }
        else                       { src = w_out;  off4 = 3670016; }
        const float4* s4 = (const float4*)src + (base4 - off4) + tid;
        float4 v[8];
#pragma unroll
        for (int i = 0; i < 8; i++) v[i] = s4[i * 256];
        f16x4* d4 = (f16x4*)dst + base4 + tid;
#pragma unroll
        for (int i = 0; i < 8; i++) {
            f16x4 h = { (_Float16)v[i].x, (_Float16)v[i].y,
                        (_Float16)v[i].z, (_Float16)v[i].w };
            d4[i * 256] = h;
        }
        return;
    }
    const int s = bid - 2304;
    *(float4*)&xs[tid * 8]     = *(const float4*)&x[(long)s * 2048 + tid * 8];
    *(float4*)&xs[tid * 8 + 4] = *(const float4*)&x[(long)s * 2048 + tid * 8 + 4];
    __syncthreads();
    const int o = tid >> 3, j = tid & 7;
    const float* w = (o < 16) ? &w_beta[(long)o * 2048] : &w_alpha[(long)(o - 16) * 2048];
    float p = 0.f;
#pragma unroll 4
    for (int i = 0; i < 64; i++) {
        int d = i * 32 + j * 4;
        float4 wv = *(const float4*)&w[d];
        p += xs[d] * wv.x + xs[d + 1] * wv.y + xs[d + 2] * wv.z + xs[d + 3] * wv.w;
    }
    p += __shfl_xor(p, 1); p += __shfl_xor(p, 2); p += __shfl_xor(p, 4);
    if (j == 0) {
        if (o < 16) {
            betaB[s * 16 + o] = 1.f / (1.f + expf(-p));
        } else {
            int h = o - 16;
            float t = p + dt_bias[h];
            float sp = (t > 20.f) ? t : log1pf(expf(t));
            lalphaB[s * 16 + h] = -expf(log_A[h]) * sp;
        }
    }
}

// ---------------------------------------------------------------- GEMM: C(f16) = A * B^T, 128x192 tile, 8 waves
// grid (32,8) = 256 blocks = 1/CU exact; 512 threads = 2 waves/SIMD so one wave's
// ds_read latency hides under the other's MFMA (m114 overlap). 3-buffer pipeline,
// counted vmcnt: waves 0-3 stage 3 loads/tile (vmcnt 3), waves 4-7 stage 2 (vmcnt 2).
__global__ __launch_bounds__(512) void gemm_bt192(const _Float16* __restrict__ A,
                                                  const _Float16* __restrict__ B,
                                                  _Float16* __restrict__ C, int N, int K) {
    __shared__ _Float16 S[3][320 * 32];   // rows 0..127 A, 128..319 B
    const int tid = threadIdx.x;
    const int rowA0 = blockIdx.y * 128, rowB0 = blockIdx.x * 192;
    const int lane = tid & 63, wv = tid >> 6;
    const int rw = (wv & 1) * 64, cw = (wv >> 1) * 48;
    const int fr = lane & 15, kof = (lane >> 4) * 8, quad = lane >> 4;

    // staging slots: idx = tid + 512*i, idx < 1280 (waves 0-3: 3 loads, waves 4-7: 2)
    const _Float16* gp[3];
    int sidx[3];
#pragma unroll
    for (int i = 0; i < 3; i++) {
        int idx = tid + 512 * i;
        if (idx < 1280) {
            int row = idx >> 2, c0 = (idx & 3) * 8;
            gp[i] = (row < 128) ? A + (long)(rowA0 + row) * K + c0
                                : B + (long)(rowB0 + row - 128) * K + c0;
            sidx[i] = idx;
        } else { gp[i] = nullptr; sidx[i] = 0; }
    }
    const int NT = K >> 5;

    // prologue: stage tiles 0,1
#pragma unroll
    for (int i = 0; i < 3; i++)
        if (gp[i]) gload_lds16(gp[i], &S[0][sidx[i] * 8]);
#pragma unroll
    for (int i = 0; i < 3; i++)
        if (gp[i]) gload_lds16(gp[i] + 32, &S[1][sidx[i] * 8]);
    if (tid < 256) { asm volatile("s_waitcnt vmcnt(3)" ::: "memory"); }
    else           { asm volatile("s_waitcnt vmcnt(2)" ::: "memory"); }
    __builtin_amdgcn_s_barrier();

    f32x4 zero = {0.f, 0.f, 0.f, 0.f};
    f32x4 acc[4][3];
#pragma unroll
    for (int mi = 0; mi < 4; mi++)
#pragma unroll
        for (int ni = 0; ni < 3; ni++) acc[mi][ni] = zero;

    int cur = 0;
    for (int t = 0; t < NT; ++t) {
        if (t + 2 < NT) {
            int nb = cur + 2; if (nb >= 3) nb -= 3;
#pragma unroll
            for (int i = 0; i < 3; i++)
                if (gp[i]) gload_lds16(gp[i] + (t + 2) * 32, &S[nb][sidx[i] * 8]);
        }
        f16x8 af[4], bf[3];
#pragma unroll
        for (int mi = 0; mi < 4; mi++)
            af[mi] = *(const f16x8*)&S[cur][(rw + mi * 16 + fr) * 32 + kof];
#pragma unroll
        for (int ni = 0; ni < 3; ni++)
            bf[ni] = *(const f16x8*)&S[cur][(128 + cw + ni * 16 + fr) * 32 + kof];
#pragma unroll
        for (int mi = 0; mi < 4; mi++)
#pragma unroll
            for (int ni = 0; ni < 3; ni++)
                acc[mi][ni] = MFMA16(af[mi], bf[ni], acc[mi][ni]);
        if (t + 2 < NT) {
            if (tid < 256) { asm volatile("s_waitcnt vmcnt(3)" ::: "memory"); }
            else           { asm volatile("s_waitcnt vmcnt(2)" ::: "memory"); }
        } else {
            asm volatile("s_waitcnt vmcnt(0)" ::: "memory");
        }
        __builtin_amdgcn_s_barrier();
        cur = (cur == 2) ? 0 : cur + 1;
    }
    const int rbase = quad * 4;
#pragma unroll
    for (int mi = 0; mi < 4; mi++)
#pragma unroll
        for (int ni = 0; ni < 3; ni++) {
            int row = rowA0 + rw + mi * 16 + rbase;
            int col = rowB0 + cw + ni * 16 + fr;
#pragma unroll
            for (int r = 0; r < 4; r++)
                C[(long)(row + r) * N + col] = (_Float16)acc[mi][ni][r];
        }
}

// ---------------------------------------------------------------- GEMM: C(f32) = A * B^T, 64x64 tile
// Same 3-buffer counted-vmcnt pipeline. Grid (32,16) = 2/CU even.
__global__ __launch_bounds__(256) void gemm_bt6464(const _Float16* __restrict__ A,
                                                   const _Float16* __restrict__ B,
                                                   float* __restrict__ C, int N, int K) {
    __shared__ _Float16 S[3][128 * 32];   // rows 0..63 A, 64..127 B
    const int tid = threadIdx.x;
    const int rowA0 = blockIdx.y * 64, rowB0 = blockIdx.x * 64;
    const int lane = tid & 63, wv = tid >> 6;
    const int rw = (wv & 1) * 32, cwol = (wv >> 1) * 32;
    const int fr = lane & 15, kof = (lane >> 4) * 8, quad = lane >> 4;

    const _Float16* gp[2];
#pragma unroll
    for (int i = 0; i < 2; i++) {
        int idx = tid + 256 * i;
        int row = idx >> 2, c0 = (idx & 3) * 8;
        gp[i] = (row < 64) ? A + (long)(rowA0 + row) * K + c0
                           : B + (long)(rowB0 + row - 64) * K + c0;
    }
    const int NT = K >> 5;

#pragma unroll
    for (int i = 0; i < 2; i++) gload_lds16(gp[i], &S[0][(tid + 256 * i) * 8]);
#pragma unroll
    for (int i = 0; i < 2; i++) gload_lds16(gp[i] + 32, &S[1][(tid + 256 * i) * 8]);
    asm volatile("s_waitcnt vmcnt(2)" ::: "memory");
    __builtin_amdgcn_s_barrier();

    f32x4 zero = {0.f, 0.f, 0.f, 0.f};
    f32x4 acc[2][2];
#pragma unroll
    for (int mi = 0; mi < 2; mi++)
#pragma unroll
        for (int ni = 0; ni < 2; ni++) acc[mi][ni] = zero;

    int cur = 0;
    for (int t = 0; t < NT; ++t) {
        if (t + 2 < NT) {
            int nb = cur + 2; if (nb >= 3) nb -= 3;
#pragma unroll
            for (int i = 0; i < 2; i++)
                gload_lds16(gp[i] + (t + 2) * 32, &S[nb][(tid + 256 * i) * 8]);
        }
        f16x8 af[2], bf[2];
#pragma unroll
        for (int mi = 0; mi < 2; mi++)
            af[mi] = *(const f16x8*)&S[cur][(rw + mi * 16 + fr) * 32 + kof];
#pragma unroll
        for (int ni = 0; ni < 2; ni++)
            bf[ni] = *(const f16x8*)&S[cur][(64 + cwol + ni * 16 + fr) * 32 + kof];
#pragma unroll
        for (int mi = 0; mi < 2; mi++)
#pragma unroll
            for (int ni = 0; ni < 2; ni++)
                acc[mi][ni] = MFMA16(af[mi], bf[ni], acc[mi][ni]);
        if (t + 2 < NT) { asm volatile("s_waitcnt vmcnt(2)" ::: "memory"); }
        else            { asm volatile("s_waitcnt vmcnt(0)" ::: "memory"); }
        __builtin_amdgcn_s_barrier();
        cur = (cur == 2) ? 0 : cur + 1;
    }
    const int rbase = quad * 4;
#pragma unroll
    for (int mi = 0; mi < 2; mi++)
#pragma unroll
        for (int ni = 0; ni < 2; ni++) {
            int row = rowA0 + rw + mi * 16 + rbase;
            int col = rowB0 + cwol + ni * 16 + fr;
#pragma unroll
            for (int r = 0; r < 4; r++)
                C[(long)(row + r) * N + col] = acc[mi][ni][r];
        }
}

// ---------------------------------------------------------------- chunk front: conv+silu+l2norm
// + gamma cumsum + QT/KT/M/T + dual register-resident forward substitution.
__global__ __launch_bounds__(512) void chunk_front(const _Float16* __restrict__ pre,
                                                   const float* __restrict__ cw,
                                                   const float* __restrict__ betaB,
                                                   const float* __restrict__ lalphaB,
                                                   _Float16* __restrict__ Mw,
                                                   _Float16* __restrict__ QTw,
                                                   _Float16* __restrict__ KTw,
                                                   _Float16* __restrict__ WTw,
                                                   _Float16* __restrict__ Bw,
                                                   _Float16* __restrict__ BTw,
                                                   float* __restrict__ gamC) {
    __shared__ _Float16 Kh[64 * 136];
    __shared__ _Float16 Qh[64 * 136];
    __shared__ _Float16 Vh[64 * 136];
    __shared__ _Float16 Tl[64 * 72];
    __shared__ float lg[64], betL[64], bgamL[64], egQ[64], egKr[64];
    const int hc = blockIdx.x, h = hc >> 4, c = hc & 15, hq = h >> 1, s0 = c * 64;
    const int tid = threadIdx.x;

    if (tid < 64) {
        float la = lalphaB[(s0 + tid) * 16 + h];
#pragma unroll
        for (int d = 1; d < 64; d <<= 1) {
            float tv = __shfl_up(la, d, 64);
            if (tid >= d) la += tv;
        }
        lg[tid] = la;
        float la63 = __shfl(la, 63, 64);
        float b = betaB[(s0 + tid) * 16 + h];
        float eg = expf(la);
        betL[tid] = b;
        bgamL[tid] = b * eg;
        egQ[tid] = eg;
        egKr[tid] = expf(la63 - la);
        if (tid == 63) gamC[hc] = eg;
    }

    // ---- causal conv(K=4)+SiLU (+l2 norm for q,k) -> LDS (padded stride 136), f16
    {
        const int tt = tid >> 3, pp = tid & 7, m0 = pp * 16;
        const _Float16* rp[4];
        bool ok0, ok1, ok2;
        {
            int sb = s0 + tt - 3;
            ok0 = (sb >= 0); ok1 = (sb + 1 >= 0); ok2 = (sb + 2 >= 0);
            rp[0] = pre + (long)sb * 6144;
            rp[1] = pre + (long)(sb + 1) * 6144;
            rp[2] = pre + (long)(sb + 2) * 6144;
            rp[3] = pre + (long)(sb + 3) * 6144;
        }
#pragma unroll
        for (int sel = 0; sel < 3; sel++) {
            const int colbase = (sel == 0) ? hq * 128 : (sel == 1) ? 1024 + hq * 128
                                                                   : 2048 + h * 128;
            float vals[16];
            float ss = 0.f;
#pragma unroll
            for (int g = 0; g < 2; g++) {
                const int co = colbase + m0 + g * 8;
                f16x8 r0 = {}, r1 = {}, r2 = {}, r3;
                if (ok0) r0 = *(const f16x8*)&rp[0][co];
                if (ok1) r1 = *(const f16x8*)&rp[1][co];
                if (ok2) r2 = *(const f16x8*)&rp[2][co];
                r3 = *(const f16x8*)&rp[3][co];
#pragma unroll
                for (int j = 0; j < 8; j++) {
                    float4 w = *(const float4*)&cw[(co + j) * 4];
                    float a = (float)r0[j] * w.x + (float)r1[j] * w.y +
                              (float)r2[j] * w.z + (float)r3[j] * w.w;
                    a = silu_f(a);
                    vals[g * 8 + j] = a;
                    ss += a * a;
                }
            }
            float sc = 1.f;
            if (sel < 2) {
                ss += __shfl_xor(ss, 1); ss += __shfl_xor(ss, 2); ss += __shfl_xor(ss, 4);
                sc = rsqrtf(ss + 1e-6f);
                if (sel == 0) sc *= 0.08838834764831843f;  // 1/sqrt(128), queries
            }
            _Float16* dst = (sel == 0) ? Qh : (sel == 1) ? Kh : Vh;
#pragma unroll
            for (int g = 0; g < 2; g++) {
                f16x8 hv;
#pragma unroll
                for (int j = 0; j < 8; j++) hv[j] = (_Float16)(vals[g * 8 + j] * sc);
                *(f16x8*)&dst[tt * 136 + m0 + g * 8] = hv;
            }
        }
    }
    __syncthreads();

    // ---- T (LDS, waves 0-3) and M (global, waves 4-7) via MFMA
    const int wv = tid >> 6, lane = tid & 63;
    const int fr = lane & 15, kof = (lane >> 4) * 8, quad = lane >> 4;
    {
        f32x4 zero = {0.f, 0.f, 0.f, 0.f};
        if (wv < 4) {
            f32x4 accT[4];
#pragma unroll
            for (int ci = 0; ci < 4; ci++) accT[ci] = zero;
            for (int k0 = 0; k0 < 128; k0 += 32) {
                f16x8 ak = *(const f16x8*)&Kh[(wv * 16 + fr) * 136 + k0 + kof];
#pragma unroll
                for (int ci = 0; ci < 4; ci++)
                    accT[ci] = MFMA16(ak, *(const f16x8*)&Kh[(ci * 16 + fr) * 136 + k0 + kof], accT[ci]);
            }
#pragma unroll
            for (int ci = 0; ci < 4; ci++)
#pragma unroll
                for (int r = 0; r < 4; r++) {
                    int t = wv * 16 + quad * 4 + r, i = ci * 16 + fr;
                    float e = expf(lg[t] - lg[i]);
                    Tl[t * 72 + i] = (_Float16)((i < t) ? betL[t] * e * accT[ci][r] : 0.f);
                }
        } else {
            const int w = wv - 4;
            f32x4 accM[4];
#pragma unroll
            for (int ci = 0; ci < 4; ci++) accM[ci] = zero;
            for (int k0 = 0; k0 < 128; k0 += 32) {
                f16x8 aq = *(const f16x8*)&Qh[(w * 16 + fr) * 136 + k0 + kof];
#pragma unroll
                for (int ci = 0; ci < 4; ci++)
                    accM[ci] = MFMA16(aq, *(const f16x8*)&Kh[(ci * 16 + fr) * 136 + k0 + kof], accM[ci]);
            }
#pragma unroll
            for (int ci = 0; ci < 4; ci++)
#pragma unroll
                for (int r = 0; r < 4; r++) {
                    int t = w * 16 + quad * 4 + r, i = ci * 16 + fr;
                    float e = expf(lg[t] - lg[i]);
                    Mw[(long)hc * 4096 + t * 64 + i] = (_Float16)((i <= t) ? e * accM[ci][r] : 0.f);
                }
        }
    }
    __syncthreads();

    // ---- phase 3: register-resident dual forward substitution + QT/KT writes, concurrent
    if (wv < 4) {
        const int jcol = tid & 127;
        const _Float16* Xsrc = (wv < 2) ? Vh : Kh;
        const float* dscale = (wv < 2) ? betL : bgamL;
        float Xs[64];
#pragma unroll
        for (int t = 0; t < 64; t++) Xs[t] = dscale[t] * (float)Xsrc[t * 136 + jcol];
#pragma unroll
        for (int a = 0; a < 4; a++) {
#pragma unroll
            for (int b = 0; b < a; b++) {
#pragma unroll
                for (int r = 0; r < 16; r++) {
                    const _Float16* trow = &Tl[(a * 16 + r) * 72 + b * 16];
                    f16x8 t0 = *(const f16x8*)trow;
                    f16x8 t1 = *(const f16x8*)(trow + 8);
                    float acc = 0.f;
#pragma unroll
                    for (int k = 0; k < 8; k++) acc += (float)t0[k] * Xs[b * 16 + k];
#pragma unroll
                    for (int k = 0; k < 8; k++) acc += (float)t1[k] * Xs[b * 16 + 8 + k];
                    Xs[a * 16 + r] -= acc;
                }
            }
#pragma unroll
            for (int sp = 1; sp < 16; sp++) {
                const _Float16* trow = &Tl[(a * 16 + sp) * 72 + a * 16];
                f16x8 t0 = *(const f16x8*)trow;
                f16x8 t1 = *(const f16x8*)(trow + 8);
                float acc = 0.f;
#pragma unroll
                for (int tp = 0; tp < 16; tp++) {
                    if (tp < sp) acc += (float)(tp < 8 ? t0[tp] : t1[tp - 8]) * Xs[a * 16 + tp];
                }
                Xs[a * 16 + sp] -= acc;
            }
        }
        if (wv < 2) {
#pragma unroll
            for (int v = 0; v < 8; v++) {
                f16x8 hv;
#pragma unroll
                for (int j = 0; j < 8; j++) hv[j] = (_Float16)Xs[v * 8 + j];
                *(f16x8*)&WTw[((long)hc * 128 + jcol) * 64 + v * 8] = hv;
            }
        } else {
#pragma unroll
            for (int t = 0; t < 64; t++) Bw[(long)hc * 8192 + t * 128 + jcol] = (_Float16)Xs[t];
#pragma unroll
            for (int v = 0; v < 8; v++) {
                f16x8 hv;
#pragma unroll
                for (int j = 0; j < 8; j++) hv[j] = (_Float16)Xs[v * 8 + j];
                *(f16x8*)&BTw[((long)hc * 128 + jcol) * 64 + v * 8] = hv;
            }
        }
    } else {
        const int w = wv - 4;
        // QT: rows w*16..w*16+15, scaled by egQ[t]
#pragma unroll
        for (int cp = 0; cp < 4; cp++) {
            int t = w * 16 + fr;
            int cc = cp * 32 + kof;
            f16x8 q = *(const f16x8*)&Qh[t * 136 + cc];
            float s = egQ[t];
            f16x8 o;
#pragma unroll
            for (int j = 0; j < 8; j++) o[j] = (_Float16)(s * (float)q[j]);
            *(f16x8*)&QTw[(long)hc * 8192 + t * 128 + cc] = o;
        }
        // KT: transposed Kh scaled by egKr[t]
        const int m = w * 32 + (lane & 31);
        const int tb = (lane >> 5) * 8;
#pragma unroll
        for (int tp = 0; tp < 4; tp++) {
            int t0 = tb + tp * 16;
            f16x8 o;
#pragma unroll
            for (int j = 0; j < 8; j++)
                o[j] = (_Float16)(egKr[t0 + j] * (float)Kh[(t0 + j) * 136 + m]);
            *(f16x8*)&KTw[(long)hc * 8192 + m * 64 + t0] = o;
        }
    }
}

// ---------------------------------------------------------------- G = K~^T B (f16), Rt = (K~^T W)^T (f32)
__global__ __launch_bounds__(256) void gr_kernel(const _Float16* __restrict__ KTw,
                                                 const _Float16* __restrict__ BTw,
                                                 const _Float16* __restrict__ WTw,
                                                 _Float16* __restrict__ Gw,
                                                 float* __restrict__ Rtw) {
    __shared__ _Float16 KTl[128 * 72], BTl[128 * 72], WTl[128 * 72];
    const long hc = blockIdx.x;
    const int tid = threadIdx.x;
    {
        int r = tid >> 1, c0 = (tid & 1) * 32;
        const _Float16* k_ = &KTw[hc * 8192 + r * 64 + c0];
        const _Float16* b_ = &BTw[hc * 8192 + r * 64 + c0];
        const _Float16* w_ = &WTw[hc * 8192 + r * 64 + c0];
#pragma unroll
        for (int i = 0; i < 4; i++) {
            *(f16x8*)&KTl[r * 72 + c0 + i * 8] = *(const f16x8*)&k_[i * 8];
            *(f16x8*)&BTl[r * 72 + c0 + i * 8] = *(const f16x8*)&b_[i * 8];
            *(f16x8*)&WTl[r * 72 + c0 + i * 8] = *(const f16x8*)&w_[i * 8];
        }
    }
    __syncthreads();
    const int wv = tid >> 6, lane = tid & 63;
    const int fr = lane & 15, kof = (lane >> 4) * 8, quad = lane >> 4;
    f32x4 zero = {0.f, 0.f, 0.f, 0.f};
#pragma unroll
    for (int mi = 0; mi < 2; mi++) {
        int m0 = (wv * 2 + mi) * 16;
        f16x8 a0 = *(const f16x8*)&KTl[(m0 + fr) * 72 + kof];
        f16x8 a1 = *(const f16x8*)&KTl[(m0 + fr) * 72 + 32 + kof];
#pragma unroll
        for (int nj = 0; nj < 8; nj++) {
            f32x4 acc = zero;
            acc = MFMA16(a0, *(const f16x8*)&BTl[(nj * 16 + fr) * 72 + kof], acc);
            acc = MFMA16(a1, *(const f16x8*)&BTl[(nj * 16 + fr) * 72 + 32 + kof], acc);
#pragma unroll
            for (int r = 0; r < 4; r++)
                Gw[hc * 16384 + (long)(m0 + quad * 4 + r) * 128 + nj * 16 + fr] = (_Float16)acc[r];
        }
    }
#pragma unroll
    for (int ji = 0; ji < 2; ji++) {
        int j0 = (wv * 2 + ji) * 16;
        f16x8 a0 = *(const f16x8*)&WTl[(j0 + fr) * 72 + kof];
        f16x8 a1 = *(const f16x8*)&WTl[(j0 + fr) * 72 + 32 + kof];
#pragma unroll
        for (int nm = 0; nm < 8; nm++) {
            f32x4 acc = zero;
            acc = MFMA16(a0, *(const f16x8*)&KTl[(nm * 16 + fr) * 72 + kof], acc);
            acc = MFMA16(a1, *(const f16x8*)&KTl[(nm * 16 + fr) * 72 + 32 + kof], acc);
#pragma unroll
            for (int r = 0; r < 4; r++)
                Rtw[hc * 16384 + (long)(j0 + quad * 4 + r) * 128 + nm * 16 + fr] = acc[r];
        }
    }
}

// ---------------------------------------------------------------- serial affine state scan
__global__ __launch_bounds__(256) void serial_scan(const _Float16* __restrict__ Gw,
                                                   const float* __restrict__ Rtw,
                                                   const float* __restrict__ gamC,
                                                   float* __restrict__ Zdump) {
    __shared__ _Float16 Zhi[32 * 136], Zlo[32 * 136];
    __shared__ _Float16 Gl[128 * 136];
    const int tid = threadIdx.x;
    const int h = blockIdx.x >> 2, js = (blockIdx.x & 3) * 32;
    const int wv = tid >> 6, lane = tid & 63;
    const int fr = lane & 15, kof = (lane >> 4) * 8, quad = lane >> 4;
    const int gr_ = tid >> 1, gc_ = (tid & 1) * 64;

    for (int e = tid; e < 32 * 136; e += 256) { Zhi[e] = (_Float16)0.f; Zlo[e] = (_Float16)0.f; }
    float z[2][2][4];
#pragma unroll
    for (int jt = 0; jt < 2; jt++)
#pragma unroll
        for (int u = 0; u < 2; u++)
#pragma unroll
            for (int r = 0; r < 4; r++) z[jt][u][r] = 0.f;

    long hc0 = (long)h * 16;
    f16x8 gpre[8];
#pragma unroll
    for (int i = 0; i < 8; i++)
        gpre[i] = *(const f16x8*)&Gw[hc0 * 16384 + (long)gr_ * 128 + gc_ + i * 8];
    float rpre[2][2][4];
#pragma unroll
    for (int jt = 0; jt < 2; jt++)
#pragma unroll
        for (int u = 0; u < 2; u++)
#pragma unroll
            for (int r = 0; r < 4; r++)
                rpre[jt][u][r] = Rtw[hc0 * 16384 +
                                     (long)(js + jt * 16 + quad * 4 + r) * 128 +
                                     (2 * wv + u) * 16 + fr];
    __syncthreads();

    for (int c = 0; c < 16; ++c) {
        long hc = (long)h * 16 + c;
        float gC = gamC[hc];
#pragma unroll
        for (int i = 0; i < 8; i++)
            *(f16x8*)&Gl[gr_ * 136 + gc_ + i * 8] = gpre[i];
        long hcn = (long)h * 16 + (c < 15 ? c + 1 : 15);
        f16x8 gnext[8];
#pragma unroll
        for (int i = 0; i < 8; i++)
            gnext[i] = *(const f16x8*)&Gw[hcn * 16384 + (long)gr_ * 128 + gc_ + i * 8];
        float rnext[2][2][4];
#pragma unroll
        for (int jt = 0; jt < 2; jt++)
#pragma unroll
            for (int u = 0; u < 2; u++)
#pragma unroll
                for (int r = 0; r < 4; r++)
                    rnext[jt][u][r] = Rtw[hcn * 16384 +
                                          (long)(js + jt * 16 + quad * 4 + r) * 128 +
                                          (2 * wv + u) * 16 + fr];
        __syncthreads();
        f32x4 acc[2][2];
        f32x4 zero = {0.f, 0.f, 0.f, 0.f};
#pragma unroll
        for (int jt = 0; jt < 2; jt++)
#pragma unroll
            for (int u = 0; u < 2; u++) acc[jt][u] = zero;
        for (int k0 = 0; k0 < 128; k0 += 32) {
            f16x8 ahi[2], alo[2], bfr[2];
#pragma unroll
            for (int jt = 0; jt < 2; jt++) {
                ahi[jt] = *(const f16x8*)&Zhi[(jt * 16 + fr) * 136 + k0 + kof];
                alo[jt] = *(const f16x8*)&Zlo[(jt * 16 + fr) * 136 + k0 + kof];
            }
#pragma unroll
            for (int u = 0; u < 2; u++)
                bfr[u] = *(const f16x8*)&Gl[((2 * wv + u) * 16 + fr) * 136 + k0 + kof];
#pragma unroll
            for (int jt = 0; jt < 2; jt++)
#pragma unroll
                for (int u = 0; u < 2; u++) {
                    acc[jt][u] = MFMA16(ahi[jt], bfr[u], acc[jt][u]);
                    acc[jt][u] = MFMA16(alo[jt], bfr[u], acc[jt][u]);
                }
        }
        __syncthreads();
#pragma unroll
        for (int jt = 0; jt < 2; jt++)
#pragma unroll
            for (int u = 0; u < 2; u++)
#pragma unroll
                for (int r = 0; r < 4; r++) {
                    int j = jt * 16 + quad * 4 + r;
                    int m = (2 * wv + u) * 16 + fr;
                    Zdump[hc * 16384 + (long)(js + j) * 128 + m] = z[jt][u][r];
                    float zn = gC * z[jt][u][r] - acc[jt][u][r] + rpre[jt][u][r];
                    z[jt][u][r] = zn;
                    _Float16 hi = (_Float16)zn;
                    Zhi[j * 136 + m] = hi;
                    Zlo[j * 136 + m] = (_Float16)(zn - (float)hi);
                }
#pragma unroll
        for (int i = 0; i < 8; i++) gpre[i] = gnext[i];
#pragma unroll
        for (int jt = 0; jt < 2; jt++)
#pragma unroll
            for (int u = 0; u < 2; u++)
#pragma unroll
                for (int r = 0; r < 4; r++) rpre[jt][u][r] = rnext[jt][u][r];
    }
}

// ---------------------------------------------------------------- per-chunk output + RMS + gate, fused
// One block per hc, 512 threads (8 waves). Waves 0-3: column-half 0; waves 4-7: half 1.
__global__ __launch_bounds__(512) void out_fused(const float* __restrict__ Zdump,
                                                 const _Float16* __restrict__ Bw,
                                                 const _Float16* __restrict__ WTw,
                                                 const _Float16* __restrict__ QTw,
                                                 const _Float16* __restrict__ Mw,
                                                 const _Float16* __restrict__ pre,
                                                 const float* __restrict__ rms_w,
                                                 _Float16* __restrict__ y) {
    __shared__ _Float16 SThi[128 * 136], STlo[128 * 136];
    __shared__ _Float16 Bl[64 * 136];
    __shared__ _Float16 UT[2][64 * 72];
    __shared__ float rowsq[2][64];
    const long hc = blockIdx.x;
    const int h = (int)(hc >> 4), c = (int)(hc & 15), s0 = c * 64;
    const int tid = threadIdx.x, wv = tid >> 6, lane = tid & 63;
    const int half = wv >> 2, wvh = wv & 3, jh = half * 64;
    const int fr = lane & 15, kof = (lane >> 4) * 8, quad = lane >> 4;
    {
        int r = tid >> 2, c0 = (tid & 3) * 32;        // r: 0..127 dv rows
        const float* src = &Zdump[hc * 16384 + (long)r * 128 + c0];
#pragma unroll
        for (int i = 0; i < 8; i++) {
            float4 v = *(const float4*)&src[i * 4];
            _Float16 h0 = (_Float16)v.x, h1 = (_Float16)v.y, h2 = (_Float16)v.z, h3 = (_Float16)v.w;
            f16x4 hi = {h0, h1, h2, h3};
            f16x4 lo = {(_Float16)(v.x - (float)h0), (_Float16)(v.y - (float)h1),
                        (_Float16)(v.z - (float)h2), (_Float16)(v.w - (float)h3)};
            *(f16x4*)&SThi[r * 136 + c0 + i * 4] = hi;
            *(f16x4*)&STlo[r * 136 + c0 + i * 4] = lo;
        }
        if (tid < 256) {
            int r2 = tid >> 2, cb = (tid & 3) * 32;
            const _Float16* bsrc = &Bw[hc * 8192 + r2 * 128 + cb];
#pragma unroll
            for (int i = 0; i < 4; i++)
                *(f16x8*)&Bl[r2 * 136 + cb + i * 8] = *(const f16x8*)&bsrc[i * 8];
        }
    }
    __syncthreads();
    const int t0 = wvh * 16;
    f16x8 ba[4];
#pragma unroll
    for (int k = 0; k < 4; k++)
        ba[k] = *(const f16x8*)&Bl[(t0 + fr) * 136 + k * 32 + kof];
#pragma unroll
    for (int jt = 0; jt < 4; jt++) {
        f32x4 acc = {0.f, 0.f, 0.f, 0.f};
#pragma unroll
        for (int k = 0; k < 4; k++) {
            acc = MFMA16(ba[k], *(const f16x8*)&SThi[(jh + jt * 16 + fr) * 136 + k * 32 + kof], acc);
            acc = MFMA16(ba[k], *(const f16x8*)&STlo[(jh + jt * 16 + fr) * 136 + k * 32 + kof], acc);
        }
#pragma unroll
        for (int r = 0; r < 4; r++) {
            int t = t0 + quad * 4 + r;
            int j = jt * 16 + fr;
            float w = (float)WTw[hc * 8192 + (long)(jh + j) * 64 + t];
            UT[half][j * 72 + t] = (_Float16)(w - acc[r]);
        }
    }
    __syncthreads();
    f16x8 qa[4], ma[2];
#pragma unroll
    for (int k = 0; k < 4; k++)
        qa[k] = *(const f16x8*)&QTw[hc * 8192 + (long)(t0 + fr) * 128 + k * 32 + kof];
#pragma unroll
    for (int k = 0; k < 2; k++)
        ma[k] = *(const f16x8*)&Mw[hc * 4096 + (long)(t0 + fr) * 64 + k * 32 + kof];
    f32x4 out[4];
#pragma unroll
    for (int jt = 0; jt < 4; jt++) {
        f32x4 acc = {0.f, 0.f, 0.f, 0.f};
#pragma unroll
        for (int k = 0; k < 4; k++) {
            acc = MFMA16(qa[k], *(const f16x8*)&SThi[(jh + jt * 16 + fr) * 136 + k * 32 + kof], acc);
            acc = MFMA16(qa[k], *(const f16x8*)&STlo[(jh + jt * 16 + fr) * 136 + k * 32 + kof], acc);
        }
#pragma unroll
        for (int k = 0; k < 2; k++)
            acc = MFMA16(ma[k], *(const f16x8*)&UT[half][(jt * 16 + fr) * 72 + k * 32 + kof], acc);
        out[jt] = acc;
    }
    // ---- cross-half row RMS: partial sumsq over this half's 4 cols, reduce over fr
    float pr[4];
#pragma unroll
    for (int r = 0; r < 4; r++) {
        float s = 0.f;
#pragma unroll
        for (int jt = 0; jt < 4; jt++) s += out[jt][r] * out[jt][r];
        s += __shfl_xor(s, 1); s += __shfl_xor(s, 2);
        s += __shfl_xor(s, 4); s += __shfl_xor(s, 8);
        pr[r] = s;
    }
    if (fr == 0) {
#pragma unroll
        for (int r = 0; r < 4; r++) rowsq[half][t0 + quad * 4 + r] = pr[r];
    }
    __syncthreads();
#pragma unroll
    for (int r = 0; r < 4; r++) {
        int t = t0 + quad * 4 + r;
        float ss = rowsq[0][t] + rowsq[1][t];
        float sc = rsqrtf(ss * (1.f / 128.f) + 1e-6f);
        long rb = (long)(s0 + t) * 6144 + 4096 + h * 128 + jh;
        long yb_ = (long)(s0 + t) * 2048 + h * 128 + jh;
#pragma unroll
        for (int jt = 0; jt < 4; jt++) {
            int j = jt * 16 + fr;
            float g = silu_f((float)pre[rb + j]);
            y[yb_ + j] = (_Float16)(out[jt][r] * sc * rms_w[jh + j] * g);
        }
    }
}

// ---------------------------------------------------------------- launch
extern "C" void kernel_launch(void* const* d_in, const int* in_sizes, int n_in,
                              void* d_out, int out_size, void* d_ws, size_t ws_size,
                              hipStream_t stream) {
    const float* x       = (const float*)d_in[0];
    const float* w_qkv   = (const float*)d_in[1];
    const float* w_gate  = (const float*)d_in[2];
    const float* w_beta  = (const float*)d_in[3];
    const float* w_alpha = (const float*)d_in[4];
    const float* log_A   = (const float*)d_in[5];
    const float* dt_bias = (const float*)d_in[6];
    const float* conv_w  = (const float*)d_in[7];
    const float* rms_w   = (const float*)d_in[8];
    const float* w_out   = (const float*)d_in[9];
    float* outp = (float*)d_out;

    char* ws = (char*)d_ws;
    size_t off = 0;
    _Float16* xb     = (_Float16*)(ws + off); off += (size_t)1024 * 2048 * 2;   // | contiguous
    _Float16* wfused = (_Float16*)(ws + off); off += (size_t)6144 * 2048 * 2;   // | f16 cvt
    _Float16* woutb  = (_Float16*)(ws + off); off += (size_t)2048 * 2048 * 2;   // | region
    _Float16* yb     = (_Float16*)(ws + off); off += (size_t)1024 * 2048 * 2;
    _Float16* pre    = (_Float16*)(ws + off); off += (size_t)1024 * 6144 * 2;
    float* betaB     = (float*)(ws + off);    off += (size_t)1024 * 16 * 4;
    float* lalphaB   = (float*)(ws + off);    off += (size_t)1024 * 16 * 4;
    _Float16* Mw     = (_Float16*)(ws + off); off += (size_t)256 * 4096 * 2;
    _Float16* QTw    = (_Float16*)(ws + off); off += (size_t)256 * 8192 * 2;
    _Float16* KTw    = (_Float16*)(ws + off); off += (size_t)256 * 8192 * 2;
    _Float16* WTw    = (_Float16*)(ws + off); off += (size_t)256 * 8192 * 2;
    _Float16* Bw     = (_Float16*)(ws + off); off += (size_t)256 * 8192 * 2;
    _Float16* BTw    = (_Float16*)(ws + off); off += (size_t)256 * 8192 * 2;
    float* gamC      = (float*)(ws + off);    off += (size_t)256 * 4;
    _Float16* Gw     = (_Float16*)(ws + off); off += (size_t)256 * 16384 * 2;
    float* Rtw       = (float*)(ws + off);    off += (size_t)256 * 16384 * 4;
    float* Zdump     = (float*)(ws + off);    off += (size_t)256 * 16384 * 4;

    // all f32->f16 conversions (8 float4/thread) + beta/alpha projections, one launch
    cvt_proj<<<3328, 256, 0, stream>>>(x, w_qkv, w_gate, w_out, xb,
                                       w_beta, w_alpha, log_A, dt_bias, betaB, lalphaB);

    // fused qkv+gate projection: 128x192 tiles, 8 waves (2/SIMD), 256 blocks = 1/CU
    gemm_bt192<<<dim3(32, 8), 512, 0, stream>>>(xb, wfused, pre, 6144, 2048);

    // conv+norm+prep+solve fused: one block per (head,chunk), 8 waves
    chunk_front<<<256, 512, 0, stream>>>(pre, conv_w, betaB, lalphaB,
                                         Mw, QTw, KTw, WTw, Bw, BTw, gamC);
    gr_kernel<<<256, 256, 0, stream>>>(KTw, BTw, WTw, Gw, Rtw);
    serial_scan<<<64, 256, 0, stream>>>(Gw, Rtw, gamC, Zdump);

    // per-chunk output + RMS + gate fused: one block per hc, 8 waves
    out_fused<<<256, 512, 0, stream>>>(Zdump, Bw, WTw, QTw, Mw, pre, rms_w, yb);

    // out projection: 64x64 tiles, pipelined
    gemm_bt6464<<<dim3(32, 16), 256, 0, stream>>>(yb, woutb, outp, 2048, 2048);
}

// Round 12
// 260.492 us; speedup vs baseline: 1.0542x; 1.0465x over previous
//
#include <hip/hip_runtime.h>

#define AS1 __attribute__((address_space(1)))
#define AS3 __attribute__((address_space(3)))

typedef _Float16 f16x8 __attribute__((ext_vector_type(8)));
typedef _Float16 f16x4 __attribute__((ext_vector_type(4)));
typedef _Float16 f16x2 __attribute__((ext_vector_type(2)));
typedef float f32x4 __attribute__((ext_vector_type(4)));

#define MFMA16(a, b, c) __builtin_amdgcn_mfma_f32_16x16x32_f16((a), (b), (c), 0, 0, 0)

// ---------------------------------------------------------------- helpers
__device__ __forceinline__ float silu_f(float v) { return v / (1.f + expf(-v)); }

__device__ __forceinline__ void gload_lds16(const void* g, void* l) {
    __builtin_amdgcn_global_load_lds((AS1 void*)g, (AS3 void*)l, 16, 0, 0);
}

// ---------------------------------------------------------------- fused cvt + proj_ba
// blocks [0,2304): f32->f16 of x|w_qkv|w_gate|w_out, 8 float4/thread (MLP=8).
// blocks [2304,3328): beta / log-alpha projections
__global__ __launch_bounds__(256) void cvt_proj(const float* __restrict__ x,
                                                const float* __restrict__ w_qkv,
                                                const float* __restrict__ w_gate,
                                                const float* __restrict__ w_out,
                                                _Float16* __restrict__ dst,
                                                const float* __restrict__ w_beta,
                                                const float* __restrict__ w_alpha,
                                                const float* __restrict__ log_A,
                                                const float* __restrict__ dt_bias,
                                                float* __restrict__ betaB,
                                                float* __restrict__ lalphaB) {
    __shared__ float xs[2048];
    const int bid = blockIdx.x, tid = threadIdx.x;
    if (bid < 2304) {
        long base4 = (long)bid * 2048;   // float4 units
        const float* src; long off4;
        if (base4 < 524288)        { src = x;      off4 = 0; }
        else if (base4 < 2621440)  { src = w_qkv;  off4 = 524288; }
        else if (base4 < 3670016)  { src = w_gate; off4 = 2621440; }
        else                       { src = w_out;  off4 = 3670016; }
        const float4* s4 = (const float4*)src + (base4 - off4) + tid;
        float4 v[8];
#pragma unroll
        for (int i = 0; i < 8; i++) v[i] = s4[i * 256];
        f16x4* d4 = (f16x4*)dst + base4 + tid;
#pragma unroll
        for (int i = 0; i < 8; i++) {
            f16x4 h = { (_Float16)v[i].x, (_Float16)v[i].y,
                        (_Float16)v[i].z, (_Float16)v[i].w };
            d4[i * 256] = h;
        }
        return;
    }
    const int s = bid - 2304;
    *(float4*)&xs[tid * 8]     = *(const float4*)&x[(long)s * 2048 + tid * 8];
    *(float4*)&xs[tid * 8 + 4] = *(const float4*)&x[(long)s * 2048 + tid * 8 + 4];
    __syncthreads();
    const int o = tid >> 3, j = tid & 7;
    const float* w = (o < 16) ? &w_beta[(long)o * 2048] : &w_alpha[(long)(o - 16) * 2048];
    float p = 0.f;
#pragma unroll 4
    for (int i = 0; i < 64; i++) {
        int d = i * 32 + j * 4;
        float4 wv = *(const float4*)&w[d];
        p += xs[d] * wv.x + xs[d + 1] * wv.y + xs[d + 2] * wv.z + xs[d + 3] * wv.w;
    }
    p += __shfl_xor(p, 1); p += __shfl_xor(p, 2); p += __shfl_xor(p, 4);
    if (j == 0) {
        if (o < 16) {
            betaB[s * 16 + o] = 1.f / (1.f + expf(-p));
        } else {
            int h = o - 16;
            float t = p + dt_bias[h];
            float sp = (t > 20.f) ? t : log1pf(expf(t));
            lalphaB[s * 16 + h] = -expf(log_A[h]) * sp;
        }
    }
}

// ---------------------------------------------------------------- GEMM: C(f16) = A * B^T, 128x128 tile
// 3-buffer LDS pipeline, counted vmcnt (best measured config, round 4: 41.3 us).
__global__ __launch_bounds__(256) void gemm_bt128h(const _Float16* __restrict__ A,
                                                   const _Float16* __restrict__ B,
                                                   _Float16* __restrict__ C, int N, int K) {
    __shared__ _Float16 S[3][256 * 32];   // rows 0..127 A, 128..255 B
    const int tid = threadIdx.x;
    const int rowA0 = blockIdx.y * 128, rowB0 = blockIdx.x * 128;
    const int lane = tid & 63, wv = tid >> 6;
    const int rw = (wv & 1) * 64, cw = (wv >> 1) * 64;
    const int fr = lane & 15, kof = (lane >> 4) * 8, quad = lane >> 4;

    const _Float16* gp[4];
#pragma unroll
    for (int i = 0; i < 4; i++) {
        int idx = tid + 256 * i;
        int row = idx >> 2, c0 = (idx & 3) * 8;
        gp[i] = (row < 128) ? A + (long)(rowA0 + row) * K + c0
                            : B + (long)(rowB0 + row - 128) * K + c0;
    }
    const int NT = K >> 5;

    // prologue: stage tiles 0,1
#pragma unroll
    for (int i = 0; i < 4; i++) gload_lds16(gp[i], &S[0][(tid + 256 * i) * 8]);
#pragma unroll
    for (int i = 0; i < 4; i++) gload_lds16(gp[i] + 32, &S[1][(tid + 256 * i) * 8]);
    asm volatile("s_waitcnt vmcnt(4)" ::: "memory");
    __builtin_amdgcn_s_barrier();

    f32x4 zero = {0.f, 0.f, 0.f, 0.f};
    f32x4 acc[4][4];
#pragma unroll
    for (int mi = 0; mi < 4; mi++)
#pragma unroll
        for (int ni = 0; ni < 4; ni++) acc[mi][ni] = zero;

    int cur = 0;
    for (int t = 0; t < NT; ++t) {
        if (t + 2 < NT) {
            int nb = cur + 2; if (nb >= 3) nb -= 3;
#pragma unroll
            for (int i = 0; i < 4; i++)
                gload_lds16(gp[i] + (t + 2) * 32, &S[nb][(tid + 256 * i) * 8]);
        }
        f16x8 af[4], bf[4];
#pragma unroll
        for (int mi = 0; mi < 4; mi++)
            af[mi] = *(const f16x8*)&S[cur][(rw + mi * 16 + fr) * 32 + kof];
#pragma unroll
        for (int ni = 0; ni < 4; ni++)
            bf[ni] = *(const f16x8*)&S[cur][(128 + cw + ni * 16 + fr) * 32 + kof];
#pragma unroll
        for (int mi = 0; mi < 4; mi++)
#pragma unroll
            for (int ni = 0; ni < 4; ni++)
                acc[mi][ni] = MFMA16(af[mi], bf[ni], acc[mi][ni]);
        if (t + 2 < NT) { asm volatile("s_waitcnt vmcnt(4)" ::: "memory"); }
        else            { asm volatile("s_waitcnt vmcnt(0)" ::: "memory"); }
        __builtin_amdgcn_s_barrier();
        cur = (cur == 2) ? 0 : cur + 1;
    }
    const int rbase = quad * 4;
#pragma unroll
    for (int mi = 0; mi < 4; mi++)
#pragma unroll
        for (int ni = 0; ni < 4; ni++) {
            int row = rowA0 + rw + mi * 16 + rbase;
            int col = rowB0 + cw + ni * 16 + fr;
#pragma unroll
            for (int r = 0; r < 4; r++)
                C[(long)(row + r) * N + col] = (_Float16)acc[mi][ni][r];
        }
}

// ---------------------------------------------------------------- GEMM: C(f32) = A * B^T, 64x64 tile
// Same 3-buffer counted-vmcnt pipeline. Grid (32,16) = 2/CU even.
__global__ __launch_bounds__(256) void gemm_bt6464(const _Float16* __restrict__ A,
                                                   const _Float16* __restrict__ B,
                                                   float* __restrict__ C, int N, int K) {
    __shared__ _Float16 S[3][128 * 32];   // rows 0..63 A, 64..127 B
    const int tid = threadIdx.x;
    const int rowA0 = blockIdx.y * 64, rowB0 = blockIdx.x * 64;
    const int lane = tid & 63, wv = tid >> 6;
    const int rw = (wv & 1) * 32, cwol = (wv >> 1) * 32;
    const int fr = lane & 15, kof = (lane >> 4) * 8, quad = lane >> 4;

    const _Float16* gp[2];
#pragma unroll
    for (int i = 0; i < 2; i++) {
        int idx = tid + 256 * i;
        int row = idx >> 2, c0 = (idx & 3) * 8;
        gp[i] = (row < 64) ? A + (long)(rowA0 + row) * K + c0
                           : B + (long)(rowB0 + row - 64) * K + c0;
    }
    const int NT = K >> 5;

#pragma unroll
    for (int i = 0; i < 2; i++) gload_lds16(gp[i], &S[0][(tid + 256 * i) * 8]);
#pragma unroll
    for (int i = 0; i < 2; i++) gload_lds16(gp[i] + 32, &S[1][(tid + 256 * i) * 8]);
    asm volatile("s_waitcnt vmcnt(2)" ::: "memory");
    __builtin_amdgcn_s_barrier();

    f32x4 zero = {0.f, 0.f, 0.f, 0.f};
    f32x4 acc[2][2];
#pragma unroll
    for (int mi = 0; mi < 2; mi++)
#pragma unroll
        for (int ni = 0; ni < 2; ni++) acc[mi][ni] = zero;

    int cur = 0;
    for (int t = 0; t < NT; ++t) {
        if (t + 2 < NT) {
            int nb = cur + 2; if (nb >= 3) nb -= 3;
#pragma unroll
            for (int i = 0; i < 2; i++)
                gload_lds16(gp[i] + (t + 2) * 32, &S[nb][(tid + 256 * i) * 8]);
        }
        f16x8 af[2], bf[2];
#pragma unroll
        for (int mi = 0; mi < 2; mi++)
            af[mi] = *(const f16x8*)&S[cur][(rw + mi * 16 + fr) * 32 + kof];
#pragma unroll
        for (int ni = 0; ni < 2; ni++)
            bf[ni] = *(const f16x8*)&S[cur][(64 + cwol + ni * 16 + fr) * 32 + kof];
#pragma unroll
        for (int mi = 0; mi < 2; mi++)
#pragma unroll
            for (int ni = 0; ni < 2; ni++)
                acc[mi][ni] = MFMA16(af[mi], bf[ni], acc[mi][ni]);
        if (t + 2 < NT) { asm volatile("s_waitcnt vmcnt(2)" ::: "memory"); }
        else            { asm volatile("s_waitcnt vmcnt(0)" ::: "memory"); }
        __builtin_amdgcn_s_barrier();
        cur = (cur == 2) ? 0 : cur + 1;
    }
    const int rbase = quad * 4;
#pragma unroll
    for (int mi = 0; mi < 2; mi++)
#pragma unroll
        for (int ni = 0; ni < 2; ni++) {
            int row = rowA0 + rw + mi * 16 + rbase;
            int col = rowB0 + cwol + ni * 16 + fr;
#pragma unroll
            for (int r = 0; r < 4; r++)
                C[(long)(row + r) * N + col] = acc[mi][ni][r];
        }
}

// ---------------------------------------------------------------- chunk front: conv+silu+l2norm
// + gamma cumsum + QT/KT/M/T + dual register-resident forward substitution.
__global__ __launch_bounds__(512) void chunk_front(const _Float16* __restrict__ pre,
                                                   const float* __restrict__ cw,
                                                   const float* __restrict__ betaB,
                                                   const float* __restrict__ lalphaB,
                                                   _Float16* __restrict__ Mw,
                                                   _Float16* __restrict__ QTw,
                                                   _Float16* __restrict__ KTw,
                                                   _Float16* __restrict__ WTw,
                                                   _Float16* __restrict__ Bw,
                                                   _Float16* __restrict__ BTw,
                                                   float* __restrict__ gamC) {
    __shared__ _Float16 Kh[64 * 136];
    __shared__ _Float16 Qh[64 * 136];
    __shared__ _Float16 Vh[64 * 136];
    __shared__ _Float16 Tl[64 * 72];
    __shared__ float lg[64], betL[64], bgamL[64], egQ[64], egKr[64];
    const int hc = blockIdx.x, h = hc >> 4, c = hc & 15, hq = h >> 1, s0 = c * 64;
    const int tid = threadIdx.x;

    if (tid < 64) {
        float la = lalphaB[(s0 + tid) * 16 + h];
#pragma unroll
        for (int d = 1; d < 64; d <<= 1) {
            float tv = __shfl_up(la, d, 64);
            if (tid >= d) la += tv;
        }
        lg[tid] = la;
        float la63 = __shfl(la, 63, 64);
        float b = betaB[(s0 + tid) * 16 + h];
        float eg = expf(la);
        betL[tid] = b;
        bgamL[tid] = b * eg;
        egQ[tid] = eg;
        egKr[tid] = expf(la63 - la);
        if (tid == 63) gamC[hc] = eg;
    }

    // ---- causal conv(K=4)+SiLU (+l2 norm for q,k) -> LDS (padded stride 136), f16
    {
        const int tt = tid >> 3, pp = tid & 7, m0 = pp * 16;
        const _Float16* rp[4];
        bool ok0, ok1, ok2;
        {
            int sb = s0 + tt - 3;
            ok0 = (sb >= 0); ok1 = (sb + 1 >= 0); ok2 = (sb + 2 >= 0);
            rp[0] = pre + (long)sb * 6144;
            rp[1] = pre + (long)(sb + 1) * 6144;
            rp[2] = pre + (long)(sb + 2) * 6144;
            rp[3] = pre + (long)(sb + 3) * 6144;
        }
#pragma unroll
        for (int sel = 0; sel < 3; sel++) {
            const int colbase = (sel == 0) ? hq * 128 : (sel == 1) ? 1024 + hq * 128
                                                                   : 2048 + h * 128;
            float vals[16];
            float ss = 0.f;
#pragma unroll
            for (int g = 0; g < 2; g++) {
                const int co = colbase + m0 + g * 8;
                f16x8 r0 = {}, r1 = {}, r2 = {}, r3;
                if (ok0) r0 = *(const f16x8*)&rp[0][co];
                if (ok1) r1 = *(const f16x8*)&rp[1][co];
                if (ok2) r2 = *(const f16x8*)&rp[2][co];
                r3 = *(const f16x8*)&rp[3][co];
#pragma unroll
                for (int j = 0; j < 8; j++) {
                    float4 w = *(const float4*)&cw[(co + j) * 4];
                    float a = (float)r0[j] * w.x + (float)r1[j] * w.y +
                              (float)r2[j] * w.z + (float)r3[j] * w.w;
                    a = silu_f(a);
                    vals[g * 8 + j] = a;
                    ss += a * a;
                }
            }
            float sc = 1.f;
            if (sel < 2) {
                ss += __shfl_xor(ss, 1); ss += __shfl_xor(ss, 2); ss += __shfl_xor(ss, 4);
                sc = rsqrtf(ss + 1e-6f);
                if (sel == 0) sc *= 0.08838834764831843f;  // 1/sqrt(128), queries
            }
            _Float16* dst = (sel == 0) ? Qh : (sel == 1) ? Kh : Vh;
#pragma unroll
            for (int g = 0; g < 2; g++) {
                f16x8 hv;
#pragma unroll
                for (int j = 0; j < 8; j++) hv[j] = (_Float16)(vals[g * 8 + j] * sc);
                *(f16x8*)&dst[tt * 136 + m0 + g * 8] = hv;
            }
        }
    }
    __syncthreads();

    // ---- T (LDS, waves 0-3) and M (global, waves 4-7) via MFMA
    const int wv = tid >> 6, lane = tid & 63;
    const int fr = lane & 15, kof = (lane >> 4) * 8, quad = lane >> 4;
    {
        f32x4 zero = {0.f, 0.f, 0.f, 0.f};
        if (wv < 4) {
            f32x4 accT[4];
#pragma unroll
            for (int ci = 0; ci < 4; ci++) accT[ci] = zero;
            for (int k0 = 0; k0 < 128; k0 += 32) {
                f16x8 ak = *(const f16x8*)&Kh[(wv * 16 + fr) * 136 + k0 + kof];
#pragma unroll
                for (int ci = 0; ci < 4; ci++)
                    accT[ci] = MFMA16(ak, *(const f16x8*)&Kh[(ci * 16 + fr) * 136 + k0 + kof], accT[ci]);
            }
#pragma unroll
            for (int ci = 0; ci < 4; ci++)
#pragma unroll
                for (int r = 0; r < 4; r++) {
                    int t = wv * 16 + quad * 4 + r, i = ci * 16 + fr;
                    float e = expf(lg[t] - lg[i]);
                    Tl[t * 72 + i] = (_Float16)((i < t) ? betL[t] * e * accT[ci][r] : 0.f);
                }
        } else {
            const int w = wv - 4;
            f32x4 accM[4];
#pragma unroll
            for (int ci = 0; ci < 4; ci++) accM[ci] = zero;
            for (int k0 = 0; k0 < 128; k0 += 32) {
                f16x8 aq = *(const f16x8*)&Qh[(w * 16 + fr) * 136 + k0 + kof];
#pragma unroll
                for (int ci = 0; ci < 4; ci++)
                    accM[ci] = MFMA16(aq, *(const f16x8*)&Kh[(ci * 16 + fr) * 136 + k0 + kof], accM[ci]);
            }
#pragma unroll
            for (int ci = 0; ci < 4; ci++)
#pragma unroll
                for (int r = 0; r < 4; r++) {
                    int t = w * 16 + quad * 4 + r, i = ci * 16 + fr;
                    float e = expf(lg[t] - lg[i]);
                    Mw[(long)hc * 4096 + t * 64 + i] = (_Float16)((i <= t) ? e * accM[ci][r] : 0.f);
                }
        }
    }
    __syncthreads();

    // ---- phase 3: register-resident dual forward substitution + QT/KT writes, concurrent
    if (wv < 4) {
        const int jcol = tid & 127;
        const _Float16* Xsrc = (wv < 2) ? Vh : Kh;
        const float* dscale = (wv < 2) ? betL : bgamL;
        float Xs[64];
#pragma unroll
        for (int t = 0; t < 64; t++) Xs[t] = dscale[t] * (float)Xsrc[t * 136 + jcol];
#pragma unroll
        for (int a = 0; a < 4; a++) {
#pragma unroll
            for (int b = 0; b < a; b++) {
#pragma unroll
                for (int r = 0; r < 16; r++) {
                    const _Float16* trow = &Tl[(a * 16 + r) * 72 + b * 16];
                    f16x8 t0 = *(const f16x8*)trow;
                    f16x8 t1 = *(const f16x8*)(trow + 8);
                    float acc = 0.f;
#pragma unroll
                    for (int k = 0; k < 8; k++) acc += (float)t0[k] * Xs[b * 16 + k];
#pragma unroll
                    for (int k = 0; k < 8; k++) acc += (float)t1[k] * Xs[b * 16 + 8 + k];
                    Xs[a * 16 + r] -= acc;
                }
            }
#pragma unroll
            for (int sp = 1; sp < 16; sp++) {
                const _Float16* trow = &Tl[(a * 16 + sp) * 72 + a * 16];
                f16x8 t0 = *(const f16x8*)trow;
                f16x8 t1 = *(const f16x8*)(trow + 8);
                float acc = 0.f;
#pragma unroll
                for (int tp = 0; tp < 16; tp++) {
                    if (tp < sp) acc += (float)(tp < 8 ? t0[tp] : t1[tp - 8]) * Xs[a * 16 + tp];
                }
                Xs[a * 16 + sp] -= acc;
            }
        }
        if (wv < 2) {
#pragma unroll
            for (int v = 0; v < 8; v++) {
                f16x8 hv;
#pragma unroll
                for (int j = 0; j < 8; j++) hv[j] = (_Float16)Xs[v * 8 + j];
                *(f16x8*)&WTw[((long)hc * 128 + jcol) * 64 + v * 8] = hv;
            }
        } else {
#pragma unroll
            for (int t = 0; t < 64; t++) Bw[(long)hc * 8192 + t * 128 + jcol] = (_Float16)Xs[t];
#pragma unroll
            for (int v = 0; v < 8; v++) {
                f16x8 hv;
#pragma unroll
                for (int j = 0; j < 8; j++) hv[j] = (_Float16)Xs[v * 8 + j];
                *(f16x8*)&BTw[((long)hc * 128 + jcol) * 64 + v * 8] = hv;
            }
        }
    } else {
        const int w = wv - 4;
        // QT: rows w*16..w*16+15, scaled by egQ[t]
#pragma unroll
        for (int cp = 0; cp < 4; cp++) {
            int t = w * 16 + fr;
            int cc = cp * 32 + kof;
            f16x8 q = *(const f16x8*)&Qh[t * 136 + cc];
            float s = egQ[t];
            f16x8 o;
#pragma unroll
            for (int j = 0; j < 8; j++) o[j] = (_Float16)(s * (float)q[j]);
            *(f16x8*)&QTw[(long)hc * 8192 + t * 128 + cc] = o;
        }
        // KT: transposed Kh scaled by egKr[t]
        const int m = w * 32 + (lane & 31);
        const int tb = (lane >> 5) * 8;
#pragma unroll
        for (int tp = 0; tp < 4; tp++) {
            int t0 = tb + tp * 16;
            f16x8 o;
#pragma unroll
            for (int j = 0; j < 8; j++)
                o[j] = (_Float16)(egKr[t0 + j] * (float)Kh[(t0 + j) * 136 + m]);
            *(f16x8*)&KTw[(long)hc * 8192 + m * 64 + t0] = o;
        }
    }
}

// ---------------------------------------------------------------- G = K~^T B (f16), Rt = (K~^T W)^T (f32)
__global__ __launch_bounds__(256) void gr_kernel(const _Float16* __restrict__ KTw,
                                                 const _Float16* __restrict__ BTw,
                                                 const _Float16* __restrict__ WTw,
                                                 _Float16* __restrict__ Gw,
                                                 float* __restrict__ Rtw) {
    __shared__ _Float16 KTl[128 * 72], BTl[128 * 72], WTl[128 * 72];
    const long hc = blockIdx.x;
    const int tid = threadIdx.x;
    {
        int r = tid >> 1, c0 = (tid & 1) * 32;
        const _Float16* k_ = &KTw[hc * 8192 + r * 64 + c0];
        const _Float16* b_ = &BTw[hc * 8192 + r * 64 + c0];
        const _Float16* w_ = &WTw[hc * 8192 + r * 64 + c0];
#pragma unroll
        for (int i = 0; i < 4; i++) {
            *(f16x8*)&KTl[r * 72 + c0 + i * 8] = *(const f16x8*)&k_[i * 8];
            *(f16x8*)&BTl[r * 72 + c0 + i * 8] = *(const f16x8*)&b_[i * 8];
            *(f16x8*)&WTl[r * 72 + c0 + i * 8] = *(const f16x8*)&w_[i * 8];
        }
    }
    __syncthreads();
    const int wv = tid >> 6, lane = tid & 63;
    const int fr = lane & 15, kof = (lane >> 4) * 8, quad = lane >> 4;
    f32x4 zero = {0.f, 0.f, 0.f, 0.f};
#pragma unroll
    for (int mi = 0; mi < 2; mi++) {
        int m0 = (wv * 2 + mi) * 16;
        f16x8 a0 = *(const f16x8*)&KTl[(m0 + fr) * 72 + kof];
        f16x8 a1 = *(const f16x8*)&KTl[(m0 + fr) * 72 + 32 + kof];
#pragma unroll
        for (int nj = 0; nj < 8; nj++) {
            f32x4 acc = zero;
            acc = MFMA16(a0, *(const f16x8*)&BTl[(nj * 16 + fr) * 72 + kof], acc);
            acc = MFMA16(a1, *(const f16x8*)&BTl[(nj * 16 + fr) * 72 + 32 + kof], acc);
#pragma unroll
            for (int r = 0; r < 4; r++)
                Gw[hc * 16384 + (long)(m0 + quad * 4 + r) * 128 + nj * 16 + fr] = (_Float16)acc[r];
        }
    }
#pragma unroll
    for (int ji = 0; ji < 2; ji++) {
        int j0 = (wv * 2 + ji) * 16;
        f16x8 a0 = *(const f16x8*)&WTl[(j0 + fr) * 72 + kof];
        f16x8 a1 = *(const f16x8*)&WTl[(j0 + fr) * 72 + 32 + kof];
#pragma unroll
        for (int nm = 0; nm < 8; nm++) {
            f32x4 acc = zero;
            acc = MFMA16(a0, *(const f16x8*)&KTl[(nm * 16 + fr) * 72 + kof], acc);
            acc = MFMA16(a1, *(const f16x8*)&KTl[(nm * 16 + fr) * 72 + 32 + kof], acc);
#pragma unroll
            for (int r = 0; r < 4; r++)
                Rtw[hc * 16384 + (long)(j0 + quad * 4 + r) * 128 + nm * 16 + fr] = acc[r];
        }
    }
}

// ---------------------------------------------------------------- serial affine state scan
// Grid 128 = h(16) x js(8 of 16 rows) -> doubles CU coverage vs the 64-block version.
// Each block owns z[16][128]; k-sum runs over its own full m-range so j-split is exact.
__global__ __launch_bounds__(256) void serial_scan(const _Float16* __restrict__ Gw,
                                                   const float* __restrict__ Rtw,
                                                   const float* __restrict__ gamC,
                                                   float* __restrict__ Zdump) {
    __shared__ _Float16 Zhi[16 * 136], Zlo[16 * 136];
    __shared__ _Float16 Gl[128 * 136];
    const int tid = threadIdx.x;
    const int h = blockIdx.x >> 3, js = (blockIdx.x & 7) * 16;
    const int wv = tid >> 6, lane = tid & 63;
    const int fr = lane & 15, kof = (lane >> 4) * 8, quad = lane >> 4;
    const int gr_ = tid >> 1, gc_ = (tid & 1) * 64;

    for (int e = tid; e < 16 * 136; e += 256) { Zhi[e] = (_Float16)0.f; Zlo[e] = (_Float16)0.f; }
    float z[2][4];
#pragma unroll
    for (int u = 0; u < 2; u++)
#pragma unroll
        for (int r = 0; r < 4; r++) z[u][r] = 0.f;

    long hc0 = (long)h * 16;
    f16x8 gpre[8];
#pragma unroll
    for (int i = 0; i < 8; i++)
        gpre[i] = *(const f16x8*)&Gw[hc0 * 16384 + (long)gr_ * 128 + gc_ + i * 8];
    float rpre[2][4];
#pragma unroll
    for (int u = 0; u < 2; u++)
#pragma unroll
        for (int r = 0; r < 4; r++)
            rpre[u][r] = Rtw[hc0 * 16384 +
                             (long)(js + quad * 4 + r) * 128 + (2 * wv + u) * 16 + fr];
    __syncthreads();

    for (int c = 0; c < 16; ++c) {
        long hc = (long)h * 16 + c;
        float gC = gamC[hc];
#pragma unroll
        for (int i = 0; i < 8; i++)
            *(f16x8*)&Gl[gr_ * 136 + gc_ + i * 8] = gpre[i];
        long hcn = (long)h * 16 + (c < 15 ? c + 1 : 15);
        f16x8 gnext[8];
#pragma unroll
        for (int i = 0; i < 8; i++)
            gnext[i] = *(const f16x8*)&Gw[hcn * 16384 + (long)gr_ * 128 + gc_ + i * 8];
        float rnext[2][4];
#pragma unroll
        for (int u = 0; u < 2; u++)
#pragma unroll
            for (int r = 0; r < 4; r++)
                rnext[u][r] = Rtw[hcn * 16384 +
                                  (long)(js + quad * 4 + r) * 128 + (2 * wv + u) * 16 + fr];
        __syncthreads();
        f32x4 acc[2];
        f32x4 zero = {0.f, 0.f, 0.f, 0.f};
#pragma unroll
        for (int u = 0; u < 2; u++) acc[u] = zero;
        for (int k0 = 0; k0 < 128; k0 += 32) {
            f16x8 ahi = *(const f16x8*)&Zhi[fr * 136 + k0 + kof];
            f16x8 alo = *(const f16x8*)&Zlo[fr * 136 + k0 + kof];
#pragma unroll
            for (int u = 0; u < 2; u++) {
                f16x8 bfr = *(const f16x8*)&Gl[((2 * wv + u) * 16 + fr) * 136 + k0 + kof];
                acc[u] = MFMA16(ahi, bfr, acc[u]);
                acc[u] = MFMA16(alo, bfr, acc[u]);
            }
        }
        __syncthreads();
#pragma unroll
        for (int u = 0; u < 2; u++)
#pragma unroll
            for (int r = 0; r < 4; r++) {
                int j = quad * 4 + r;
                int m = (2 * wv + u) * 16 + fr;
                Zdump[hc * 16384 + (long)(js + j) * 128 + m] = z[u][r];
                float zn = gC * z[u][r] - acc[u][r] + rpre[u][r];
                z[u][r] = zn;
                _Float16 hi = (_Float16)zn;
                Zhi[j * 136 + m] = hi;
                Zlo[j * 136 + m] = (_Float16)(zn - (float)hi);
            }
#pragma unroll
        for (int i = 0; i < 8; i++) gpre[i] = gnext[i];
#pragma unroll
        for (int u = 0; u < 2; u++)
#pragma unroll
            for (int r = 0; r < 4; r++) rpre[u][r] = rnext[u][r];
    }
}

// ---------------------------------------------------------------- per-chunk output + RMS + gate, fused
// One block per hc, 512 threads (8 waves). Waves 0-3: column-half 0; waves 4-7: half 1.
__global__ __launch_bounds__(512) void out_fused(const float* __restrict__ Zdump,
                                                 const _Float16* __restrict__ Bw,
                                                 const _Float16* __restrict__ WTw,
                                                 const _Float16* __restrict__ QTw,
                                                 const _Float16* __restrict__ Mw,
                                                 const _Float16* __restrict__ pre,
                                                 const float* __restrict__ rms_w,
                                                 _Float16* __restrict__ y) {
    __shared__ _Float16 SThi[128 * 136], STlo[128 * 136];
    __shared__ _Float16 Bl[64 * 136];
    __shared__ _Float16 UT[2][64 * 72];
    __shared__ float rowsq[2][64];
    const long hc = blockIdx.x;
    const int h = (int)(hc >> 4), c = (int)(hc & 15), s0 = c * 64;
    const int tid = threadIdx.x, wv = tid >> 6, lane = tid & 63;
    const int half = wv >> 2, wvh = wv & 3, jh = half * 64;
    const int fr = lane & 15, kof = (lane >> 4) * 8, quad = lane >> 4;
    {
        int r = tid >> 2, c0 = (tid & 3) * 32;        // r: 0..127 dv rows
        const float* src = &Zdump[hc * 16384 + (long)r * 128 + c0];
#pragma unroll
        for (int i = 0; i < 8; i++) {
            float4 v = *(const float4*)&src[i * 4];
            _Float16 h0 = (_Float16)v.x, h1 = (_Float16)v.y, h2 = (_Float16)v.z, h3 = (_Float16)v.w;
            f16x4 hi = {h0, h1, h2, h3};
            f16x4 lo = {(_Float16)(v.x - (float)h0), (_Float16)(v.y - (float)h1),
                        (_Float16)(v.z - (float)h2), (_Float16)(v.w - (float)h3)};
            *(f16x4*)&SThi[r * 136 + c0 + i * 4] = hi;
            *(f16x4*)&STlo[r * 136 + c0 + i * 4] = lo;
        }
        if (tid < 256) {
            int r2 = tid >> 2, cb = (tid & 3) * 32;
            const _Float16* bsrc = &Bw[hc * 8192 + r2 * 128 + cb];
#pragma unroll
            for (int i = 0; i < 4; i++)
                *(f16x8*)&Bl[r2 * 136 + cb + i * 8] = *(const f16x8*)&bsrc[i * 8];
        }
    }
    __syncthreads();
    const int t0 = wvh * 16;
    f16x8 ba[4];
#pragma unroll
    for (int k = 0; k < 4; k++)
        ba[k] = *(const f16x8*)&Bl[(t0 + fr) * 136 + k * 32 + kof];
#pragma unroll
    for (int jt = 0; jt < 4; jt++) {
        f32x4 acc = {0.f, 0.f, 0.f, 0.f};
#pragma unroll
        for (int k = 0; k < 4; k++) {
            acc = MFMA16(ba[k], *(const f16x8*)&SThi[(jh + jt * 16 + fr) * 136 + k * 32 + kof], acc);
            acc = MFMA16(ba[k], *(const f16x8*)&STlo[(jh + jt * 16 + fr) * 136 + k * 32 + kof], acc);
        }
#pragma unroll
        for (int r = 0; r < 4; r++) {
            int t = t0 + quad * 4 + r;
            int j = jt * 16 + fr;
            float w = (float)WTw[hc * 8192 + (long)(jh + j) * 64 + t];
            UT[half][j * 72 + t] = (_Float16)(w - acc[r]);
        }
    }
    __syncthreads();
    f16x8 qa[4], ma[2];
#pragma unroll
    for (int k = 0; k < 4; k++)
        qa[k] = *(const f16x8*)&QTw[hc * 8192 + (long)(t0 + fr) * 128 + k * 32 + kof];
#pragma unroll
    for (int k = 0; k < 2; k++)
        ma[k] = *(const f16x8*)&Mw[hc * 4096 + (long)(t0 + fr) * 64 + k * 32 + kof];
    f32x4 out[4];
#pragma unroll
    for (int jt = 0; jt < 4; jt++) {
        f32x4 acc = {0.f, 0.f, 0.f, 0.f};
#pragma unroll
        for (int k = 0; k < 4; k++) {
            acc = MFMA16(qa[k], *(const f16x8*)&SThi[(jh + jt * 16 + fr) * 136 + k * 32 + kof], acc);
            acc = MFMA16(qa[k], *(const f16x8*)&STlo[(jh + jt * 16 + fr) * 136 + k * 32 + kof], acc);
        }
#pragma unroll
        for (int k = 0; k < 2; k++)
            acc = MFMA16(ma[k], *(const f16x8*)&UT[half][(jt * 16 + fr) * 72 + k * 32 + kof], acc);
        out[jt] = acc;
    }
    // ---- cross-half row RMS: partial sumsq over this half's 4 cols, reduce over fr
    float pr[4];
#pragma unroll
    for (int r = 0; r < 4; r++) {
        float s = 0.f;
#pragma unroll
        for (int jt = 0; jt < 4; jt++) s += out[jt][r] * out[jt][r];
        s += __shfl_xor(s, 1); s += __shfl_xor(s, 2);
        s += __shfl_xor(s, 4); s += __shfl_xor(s, 8);
        pr[r] = s;
    }
    if (fr == 0) {
#pragma unroll
        for (int r = 0; r < 4; r++) rowsq[half][t0 + quad * 4 + r] = pr[r];
    }
    __syncthreads();
#pragma unroll
    for (int r = 0; r < 4; r++) {
        int t = t0 + quad * 4 + r;
        float ss = rowsq[0][t] + rowsq[1][t];
        float sc = rsqrtf(ss * (1.f / 128.f) + 1e-6f);
        long rb = (long)(s0 + t) * 6144 + 4096 + h * 128 + jh;
        long yb_ = (long)(s0 + t) * 2048 + h * 128 + jh;
#pragma unroll
        for (int jt = 0; jt < 4; jt++) {
            int j = jt * 16 + fr;
            float g = silu_f((float)pre[rb + j]);
            y[yb_ + j] = (_Float16)(out[jt][r] * sc * rms_w[jh + j] * g);
        }
    }
}

// ---------------------------------------------------------------- launch
extern "C" void kernel_launch(void* const* d_in, const int* in_sizes, int n_in,
                              void* d_out, int out_size, void* d_ws, size_t ws_size,
                              hipStream_t stream) {
    const float* x       = (const float*)d_in[0];
    const float* w_qkv   = (const float*)d_in[1];
    const float* w_gate  = (const float*)d_in[2];
    const float* w_beta  = (const float*)d_in[3];
    const float* w_alpha = (const float*)d_in[4];
    const float* log_A   = (const float*)d_in[5];
    const float* dt_bias = (const float*)d_in[6];
    const float* conv_w  = (const float*)d_in[7];
    const float* rms_w   = (const float*)d_in[8];
    const float* w_out   = (const float*)d_in[9];
    float* outp = (float*)d_out;

    char* ws = (char*)d_ws;
    size_t off = 0;
    _Float16* xb     = (_Float16*)(ws + off); off += (size_t)1024 * 2048 * 2;   // | contiguous
    _Float16* wfused = (_Float16*)(ws + off); off += (size_t)6144 * 2048 * 2;   // | f16 cvt
    _Float16* woutb  = (_Float16*)(ws + off); off += (size_t)2048 * 2048 * 2;   // | region
    _Float16* yb     = (_Float16*)(ws + off); off += (size_t)1024 * 2048 * 2;
    _Float16* pre    = (_Float16*)(ws + off); off += (size_t)1024 * 6144 * 2;
    float* betaB     = (float*)(ws + off);    off += (size_t)1024 * 16 * 4;
    float* lalphaB   = (float*)(ws + off);    off += (size_t)1024 * 16 * 4;
    _Float16* Mw     = (_Float16*)(ws + off); off += (size_t)256 * 4096 * 2;
    _Float16* QTw    = (_Float16*)(ws + off); off += (size_t)256 * 8192 * 2;
    _Float16* KTw    = (_Float16*)(ws + off); off += (size_t)256 * 8192 * 2;
    _Float16* WTw    = (_Float16*)(ws + off); off += (size_t)256 * 8192 * 2;
    _Float16* Bw     = (_Float16*)(ws + off); off += (size_t)256 * 8192 * 2;
    _Float16* BTw    = (_Float16*)(ws + off); off += (size_t)256 * 8192 * 2;
    float* gamC      = (float*)(ws + off);    off += (size_t)256 * 4;
    _Float16* Gw     = (_Float16*)(ws + off); off += (size_t)256 * 16384 * 2;
    float* Rtw       = (float*)(ws + off);    off += (size_t)256 * 16384 * 4;
    float* Zdump     = (float*)(ws + off);    off += (size_t)256 * 16384 * 4;

    // all f32->f16 conversions (8 float4/thread) + beta/alpha projections, one launch
    cvt_proj<<<3328, 256, 0, stream>>>(x, w_qkv, w_gate, w_out, xb,
                                       w_beta, w_alpha, log_A, dt_bias, betaB, lalphaB);

    // fused qkv+gate projection: 128x128 tiles, 3-buffer counted-vmcnt pipeline
    gemm_bt128h<<<dim3(48, 8), 256, 0, stream>>>(xb, wfused, pre, 6144, 2048);

    // conv+norm+prep+solve fused: one block per (head,chunk), 8 waves
    chunk_front<<<256, 512, 0, stream>>>(pre, conv_w, betaB, lalphaB,
                                         Mw, QTw, KTw, WTw, Bw, BTw, gamC);
    gr_kernel<<<256, 256, 0, stream>>>(KTw, BTw, WTw, Gw, Rtw);
    serial_scan<<<128, 256, 0, stream>>>(Gw, Rtw, gamC, Zdump);

    // per-chunk output + RMS + gate fused: one block per hc, 8 waves
    out_fused<<<256, 512, 0, stream>>>(Zdump, Bw, WTw, QTw, Mw, pre, rms_w, yb);

    // out projection: 64x64 tiles, pipelined
    gemm_bt6464<<<dim3(32, 16), 256, 0, stream>>>(yb, woutb, outp, 2048, 2048);
}

// Round 13
// 259.149 us; speedup vs baseline: 1.0597x; 1.0052x over previous
//
#include <hip/hip_runtime.h>

#define AS1 __attribute__((address_space(1)))
#define AS3 __attribute__((address_space(3)))

typedef _Float16 f16x8 __attribute__((ext_vector_type(8)));
typedef _Float16 f16x4 __attribute__((ext_vector_type(4)));
typedef _Float16 f16x2 __attribute__((ext_vector_type(2)));
typedef float f32x4 __attribute__((ext_vector_type(4)));

#define MFMA16(a, b, c) __builtin_amdgcn_mfma_f32_16x16x32_f16((a), (b), (c), 0, 0, 0)

// ---------------------------------------------------------------- helpers
__device__ __forceinline__ float silu_f(float v) { return v / (1.f + expf(-v)); }

__device__ __forceinline__ void gload_lds16(const void* g, void* l) {
    __builtin_amdgcn_global_load_lds((AS1 void*)g, (AS3 void*)l, 16, 0, 0);
}

// ---------------------------------------------------------------- fused cvt + proj_ba
// blocks [0,2304): f32->f16 of x|w_qkv|w_gate|w_out, 8 float4/thread (MLP=8).
// blocks [2304,3328): beta / log-alpha projections
__global__ __launch_bounds__(256) void cvt_proj(const float* __restrict__ x,
                                                const float* __restrict__ w_qkv,
                                                const float* __restrict__ w_gate,
                                                const float* __restrict__ w_out,
                                                _Float16* __restrict__ dst,
                                                const float* __restrict__ w_beta,
                                                const float* __restrict__ w_alpha,
                                                const float* __restrict__ log_A,
                                                const float* __restrict__ dt_bias,
                                                float* __restrict__ betaB,
                                                float* __restrict__ lalphaB) {
    __shared__ float xs[2048];
    const int bid = blockIdx.x, tid = threadIdx.x;
    if (bid < 2304) {
        long base4 = (long)bid * 2048;   // float4 units
        const float* src; long off4;
        if (base4 < 524288)        { src = x;      off4 = 0; }
        else if (base4 < 2621440)  { src = w_qkv;  off4 = 524288; }
        else if (base4 < 3670016)  { src = w_gate; off4 = 2621440; }
        else                       { src = w_out;  off4 = 3670016; }
        const float4* s4 = (const float4*)src + (base4 - off4) + tid;
        float4 v[8];
#pragma unroll
        for (int i = 0; i < 8; i++) v[i] = s4[i * 256];
        f16x4* d4 = (f16x4*)dst + base4 + tid;
#pragma unroll
        for (int i = 0; i < 8; i++) {
            f16x4 h = { (_Float16)v[i].x, (_Float16)v[i].y,
                        (_Float16)v[i].z, (_Float16)v[i].w };
            d4[i * 256] = h;
        }
        return;
    }
    const int s = bid - 2304;
    *(float4*)&xs[tid * 8]     = *(const float4*)&x[(long)s * 2048 + tid * 8];
    *(float4*)&xs[tid * 8 + 4] = *(const float4*)&x[(long)s * 2048 + tid * 8 + 4];
    __syncthreads();
    const int o = tid >> 3, j = tid & 7;
    const float* w = (o < 16) ? &w_beta[(long)o * 2048] : &w_alpha[(long)(o - 16) * 2048];
    float p = 0.f;
#pragma unroll 4
    for (int i = 0; i < 64; i++) {
        int d = i * 32 + j * 4;
        float4 wv = *(const float4*)&w[d];
        p += xs[d] * wv.x + xs[d + 1] * wv.y + xs[d + 2] * wv.z + xs[d + 3] * wv.w;
    }
    p += __shfl_xor(p, 1); p += __shfl_xor(p, 2); p += __shfl_xor(p, 4);
    if (j == 0) {
        if (o < 16) {
            betaB[s * 16 + o] = 1.f / (1.f + expf(-p));
        } else {
            int h = o - 16;
            float t = p + dt_bias[h];
            float sp = (t > 20.f) ? t : log1pf(expf(t));
            lalphaB[s * 16 + h] = -expf(log_A[h]) * sp;
        }
    }
}

// ---------------------------------------------------------------- GEMM: C(f16) = A * B^T, 128x128 tile
// 3-buffer counted-vmcnt pipeline + XCD-aware block swizzle (T1): 384 blocks -> each
// XCD owns a 6x8 sub-grid (6 B-panels=3MB + 8 A-panels=4MB fits its 4MB L2 working set
// vs 28MB unswizzled) -> panel re-reads hit L2 instead of L3.
__global__ __launch_bounds__(256) void gemm_bt128h(const _Float16* __restrict__ A,
                                                   const _Float16* __restrict__ B,
                                                   _Float16* __restrict__ C, int N, int K) {
    __shared__ _Float16 S[3][256 * 32];   // rows 0..127 A, 128..255 B
    const int tid = threadIdx.x;
    const int bid = blockIdx.x + 48 * blockIdx.y;   // 0..383
    const int xcd = bid & 7, local = bid >> 3;      // 8 XCDs x 48 blocks
    const int bx = xcd * 6 + (local % 6);           // B-panel 0..47
    const int by = local / 6;                       // A-panel 0..7
    const int rowA0 = by * 128, rowB0 = bx * 128;
    const int lane = tid & 63, wv = tid >> 6;
    const int rw = (wv & 1) * 64, cw = (wv >> 1) * 64;
    const int fr = lane & 15, kof = (lane >> 4) * 8, quad = lane >> 4;

    const _Float16* gp[4];
#pragma unroll
    for (int i = 0; i < 4; i++) {
        int idx = tid + 256 * i;
        int row = idx >> 2, c0 = (idx & 3) * 8;
        gp[i] = (row < 128) ? A + (long)(rowA0 + row) * K + c0
                            : B + (long)(rowB0 + row - 128) * K + c0;
    }
    const int NT = K >> 5;

    // prologue: stage tiles 0,1
#pragma unroll
    for (int i = 0; i < 4; i++) gload_lds16(gp[i], &S[0][(tid + 256 * i) * 8]);
#pragma unroll
    for (int i = 0; i < 4; i++) gload_lds16(gp[i] + 32, &S[1][(tid + 256 * i) * 8]);
    asm volatile("s_waitcnt vmcnt(4)" ::: "memory");
    __builtin_amdgcn_s_barrier();

    f32x4 zero = {0.f, 0.f, 0.f, 0.f};
    f32x4 acc[4][4];
#pragma unroll
    for (int mi = 0; mi < 4; mi++)
#pragma unroll
        for (int ni = 0; ni < 4; ni++) acc[mi][ni] = zero;

    int cur = 0;
    for (int t = 0; t < NT; ++t) {
        if (t + 2 < NT) {
            int nb = cur + 2; if (nb >= 3) nb -= 3;
#pragma unroll
            for (int i = 0; i < 4; i++)
                gload_lds16(gp[i] + (t + 2) * 32, &S[nb][(tid + 256 * i) * 8]);
        }
        f16x8 af[4], bf[4];
#pragma unroll
        for (int mi = 0; mi < 4; mi++)
            af[mi] = *(const f16x8*)&S[cur][(rw + mi * 16 + fr) * 32 + kof];
#pragma unroll
        for (int ni = 0; ni < 4; ni++)
            bf[ni] = *(const f16x8*)&S[cur][(128 + cw + ni * 16 + fr) * 32 + kof];
#pragma unroll
        for (int mi = 0; mi < 4; mi++)
#pragma unroll
            for (int ni = 0; ni < 4; ni++)
                acc[mi][ni] = MFMA16(af[mi], bf[ni], acc[mi][ni]);
        if (t + 2 < NT) { asm volatile("s_waitcnt vmcnt(4)" ::: "memory"); }
        else            { asm volatile("s_waitcnt vmcnt(0)" ::: "memory"); }
        __builtin_amdgcn_s_barrier();
        cur = (cur == 2) ? 0 : cur + 1;
    }
    const int rbase = quad * 4;
#pragma unroll
    for (int mi = 0; mi < 4; mi++)
#pragma unroll
        for (int ni = 0; ni < 4; ni++) {
            int row = rowA0 + rw + mi * 16 + rbase;
            int col = rowB0 + cw + ni * 16 + fr;
#pragma unroll
            for (int r = 0; r < 4; r++)
                C[(long)(row + r) * N + col] = (_Float16)acc[mi][ni][r];
        }
}

// ---------------------------------------------------------------- GEMM: C(f32) = A * B^T, 64x64 tile
// Same pipeline + XCD swizzle: 512 blocks -> each XCD owns a 4x16 sub-grid.
__global__ __launch_bounds__(256) void gemm_bt6464(const _Float16* __restrict__ A,
                                                   const _Float16* __restrict__ B,
                                                   float* __restrict__ C, int N, int K) {
    __shared__ _Float16 S[3][128 * 32];   // rows 0..63 A, 64..127 B
    const int tid = threadIdx.x;
    const int bid = blockIdx.x + 32 * blockIdx.y;   // 0..511
    const int xcd = bid & 7, local = bid >> 3;      // 8 XCDs x 64 blocks
    const int bx = xcd * 4 + (local & 3);           // B-panel 0..31
    const int by = local >> 2;                      // A-panel 0..15
    const int rowA0 = by * 64, rowB0 = bx * 64;
    const int lane = tid & 63, wv = tid >> 6;
    const int rw = (wv & 1) * 32, cwol = (wv >> 1) * 32;
    const int fr = lane & 15, kof = (lane >> 4) * 8, quad = lane >> 4;

    const _Float16* gp[2];
#pragma unroll
    for (int i = 0; i < 2; i++) {
        int idx = tid + 256 * i;
        int row = idx >> 2, c0 = (idx & 3) * 8;
        gp[i] = (row < 64) ? A + (long)(rowA0 + row) * K + c0
                           : B + (long)(rowB0 + row - 64) * K + c0;
    }
    const int NT = K >> 5;

#pragma unroll
    for (int i = 0; i < 2; i++) gload_lds16(gp[i], &S[0][(tid + 256 * i) * 8]);
#pragma unroll
    for (int i = 0; i < 2; i++) gload_lds16(gp[i] + 32, &S[1][(tid + 256 * i) * 8]);
    asm volatile("s_waitcnt vmcnt(2)" ::: "memory");
    __builtin_amdgcn_s_barrier();

    f32x4 zero = {0.f, 0.f, 0.f, 0.f};
    f32x4 acc[2][2];
#pragma unroll
    for (int mi = 0; mi < 2; mi++)
#pragma unroll
        for (int ni = 0; ni < 2; ni++) acc[mi][ni] = zero;

    int cur = 0;
    for (int t = 0; t < NT; ++t) {
        if (t + 2 < NT) {
            int nb = cur + 2; if (nb >= 3) nb -= 3;
#pragma unroll
            for (int i = 0; i < 2; i++)
                gload_lds16(gp[i] + (t + 2) * 32, &S[nb][(tid + 256 * i) * 8]);
        }
        f16x8 af[2], bf[2];
#pragma unroll
        for (int mi = 0; mi < 2; mi++)
            af[mi] = *(const f16x8*)&S[cur][(rw + mi * 16 + fr) * 32 + kof];
#pragma unroll
        for (int ni = 0; ni < 2; ni++)
            bf[ni] = *(const f16x8*)&S[cur][(64 + cwol + ni * 16 + fr) * 32 + kof];
#pragma unroll
        for (int mi = 0; mi < 2; mi++)
#pragma unroll
            for (int ni = 0; ni < 2; ni++)
                acc[mi][ni] = MFMA16(af[mi], bf[ni], acc[mi][ni]);
        if (t + 2 < NT) { asm volatile("s_waitcnt vmcnt(2)" ::: "memory"); }
        else            { asm volatile("s_waitcnt vmcnt(0)" ::: "memory"); }
        __builtin_amdgcn_s_barrier();
        cur = (cur == 2) ? 0 : cur + 1;
    }
    const int rbase = quad * 4;
#pragma unroll
    for (int mi = 0; mi < 2; mi++)
#pragma unroll
        for (int ni = 0; ni < 2; ni++) {
            int row = rowA0 + rw + mi * 16 + rbase;
            int col = rowB0 + cwol + ni * 16 + fr;
#pragma unroll
            for (int r = 0; r < 4; r++)
                C[(long)(row + r) * N + col] = acc[mi][ni][r];
        }
}

// ---------------------------------------------------------------- chunk front: conv+silu+l2norm
// + gamma cumsum + QT/KT/M/T + dual register-resident forward substitution.
__global__ __launch_bounds__(512) void chunk_front(const _Float16* __restrict__ pre,
                                                   const float* __restrict__ cw,
                                                   const float* __restrict__ betaB,
                                                   const float* __restrict__ lalphaB,
                                                   _Float16* __restrict__ Mw,
                                                   _Float16* __restrict__ QTw,
                                                   _Float16* __restrict__ KTw,
                                                   _Float16* __restrict__ WTw,
                                                   _Float16* __restrict__ Bw,
                                                   _Float16* __restrict__ BTw,
                                                   float* __restrict__ gamC) {
    __shared__ _Float16 Kh[64 * 136];
    __shared__ _Float16 Qh[64 * 136];
    __shared__ _Float16 Vh[64 * 136];
    __shared__ _Float16 Tl[64 * 72];
    __shared__ float lg[64], betL[64], bgamL[64], egQ[64], egKr[64];
    const int hc = blockIdx.x, h = hc >> 4, c = hc & 15, hq = h >> 1, s0 = c * 64;
    const int tid = threadIdx.x;

    if (tid < 64) {
        float la = lalphaB[(s0 + tid) * 16 + h];
#pragma unroll
        for (int d = 1; d < 64; d <<= 1) {
            float tv = __shfl_up(la, d, 64);
            if (tid >= d) la += tv;
        }
        lg[tid] = la;
        float la63 = __shfl(la, 63, 64);
        float b = betaB[(s0 + tid) * 16 + h];
        float eg = expf(la);
        betL[tid] = b;
        bgamL[tid] = b * eg;
        egQ[tid] = eg;
        egKr[tid] = expf(la63 - la);
        if (tid == 63) gamC[hc] = eg;
    }

    // ---- causal conv(K=4)+SiLU (+l2 norm for q,k) -> LDS (padded stride 136), f16
    {
        const int tt = tid >> 3, pp = tid & 7, m0 = pp * 16;
        const _Float16* rp[4];
        bool ok0, ok1, ok2;
        {
            int sb = s0 + tt - 3;
            ok0 = (sb >= 0); ok1 = (sb + 1 >= 0); ok2 = (sb + 2 >= 0);
            rp[0] = pre + (long)sb * 6144;
            rp[1] = pre + (long)(sb + 1) * 6144;
            rp[2] = pre + (long)(sb + 2) * 6144;
            rp[3] = pre + (long)(sb + 3) * 6144;
        }
#pragma unroll
        for (int sel = 0; sel < 3; sel++) {
            const int colbase = (sel == 0) ? hq * 128 : (sel == 1) ? 1024 + hq * 128
                                                                   : 2048 + h * 128;
            float vals[16];
            float ss = 0.f;
#pragma unroll
            for (int g = 0; g < 2; g++) {
                const int co = colbase + m0 + g * 8;
                f16x8 r0 = {}, r1 = {}, r2 = {}, r3;
                if (ok0) r0 = *(const f16x8*)&rp[0][co];
                if (ok1) r1 = *(const f16x8*)&rp[1][co];
                if (ok2) r2 = *(const f16x8*)&rp[2][co];
                r3 = *(const f16x8*)&rp[3][co];
#pragma unroll
                for (int j = 0; j < 8; j++) {
                    float4 w = *(const float4*)&cw[(co + j) * 4];
                    float a = (float)r0[j] * w.x + (float)r1[j] * w.y +
                              (float)r2[j] * w.z + (float)r3[j] * w.w;
                    a = silu_f(a);
                    vals[g * 8 + j] = a;
                    ss += a * a;
                }
            }
            float sc = 1.f;
            if (sel < 2) {
                ss += __shfl_xor(ss, 1); ss += __shfl_xor(ss, 2); ss += __shfl_xor(ss, 4);
                sc = rsqrtf(ss + 1e-6f);
                if (sel == 0) sc *= 0.08838834764831843f;  // 1/sqrt(128), queries
            }
            _Float16* dst = (sel == 0) ? Qh : (sel == 1) ? Kh : Vh;
#pragma unroll
            for (int g = 0; g < 2; g++) {
                f16x8 hv;
#pragma unroll
                for (int j = 0; j < 8; j++) hv[j] = (_Float16)(vals[g * 8 + j] * sc);
                *(f16x8*)&dst[tt * 136 + m0 + g * 8] = hv;
            }
        }
    }
    __syncthreads();

    // ---- T (LDS, waves 0-3) and M (global, waves 4-7) via MFMA
    const int wv = tid >> 6, lane = tid & 63;
    const int fr = lane & 15, kof = (lane >> 4) * 8, quad = lane >> 4;
    {
        f32x4 zero = {0.f, 0.f, 0.f, 0.f};
        if (wv < 4) {
            f32x4 accT[4];
#pragma unroll
            for (int ci = 0; ci < 4; ci++) accT[ci] = zero;
            for (int k0 = 0; k0 < 128; k0 += 32) {
                f16x8 ak = *(const f16x8*)&Kh[(wv * 16 + fr) * 136 + k0 + kof];
#pragma unroll
                for (int ci = 0; ci < 4; ci++)
                    accT[ci] = MFMA16(ak, *(const f16x8*)&Kh[(ci * 16 + fr) * 136 + k0 + kof], accT[ci]);
            }
#pragma unroll
            for (int ci = 0; ci < 4; ci++)
#pragma unroll
                for (int r = 0; r < 4; r++) {
                    int t = wv * 16 + quad * 4 + r, i = ci * 16 + fr;
                    float e = expf(lg[t] - lg[i]);
                    Tl[t * 72 + i] = (_Float16)((i < t) ? betL[t] * e * accT[ci][r] : 0.f);
                }
        } else {
            const int w = wv - 4;
            f32x4 accM[4];
#pragma unroll
            for (int ci = 0; ci < 4; ci++) accM[ci] = zero;
            for (int k0 = 0; k0 < 128; k0 += 32) {
                f16x8 aq = *(const f16x8*)&Qh[(w * 16 + fr) * 136 + k0 + kof];
#pragma unroll
                for (int ci = 0; ci < 4; ci++)
                    accM[ci] = MFMA16(aq, *(const f16x8*)&Kh[(ci * 16 + fr) * 136 + k0 + kof], accM[ci]);
            }
#pragma unroll
            for (int ci = 0; ci < 4; ci++)
#pragma unroll
                for (int r = 0; r < 4; r++) {
                    int t = w * 16 + quad * 4 + r, i = ci * 16 + fr;
                    float e = expf(lg[t] - lg[i]);
                    Mw[(long)hc * 4096 + t * 64 + i] = (_Float16)((i <= t) ? e * accM[ci][r] : 0.f);
                }
        }
    }
    __syncthreads();

    // ---- phase 3: register-resident dual forward substitution + QT/KT writes, concurrent
    if (wv < 4) {
        const int jcol = tid & 127;
        const _Float16* Xsrc = (wv < 2) ? Vh : Kh;
        const float* dscale = (wv < 2) ? betL : bgamL;
        float Xs[64];
#pragma unroll
        for (int t = 0; t < 64; t++) Xs[t] = dscale[t] * (float)Xsrc[t * 136 + jcol];
#pragma unroll
        for (int a = 0; a < 4; a++) {
#pragma unroll
            for (int b = 0; b < a; b++) {
#pragma unroll
                for (int r = 0; r < 16; r++) {
                    const _Float16* trow = &Tl[(a * 16 + r) * 72 + b * 16];
                    f16x8 t0 = *(const f16x8*)trow;
                    f16x8 t1 = *(const f16x8*)(trow + 8);
                    float acc = 0.f;
#pragma unroll
                    for (int k = 0; k < 8; k++) acc += (float)t0[k] * Xs[b * 16 + k];
#pragma unroll
                    for (int k = 0; k < 8; k++) acc += (float)t1[k] * Xs[b * 16 + 8 + k];
                    Xs[a * 16 + r] -= acc;
                }
            }
#pragma unroll
            for (int sp = 1; sp < 16; sp++) {
                const _Float16* trow = &Tl[(a * 16 + sp) * 72 + a * 16];
                f16x8 t0 = *(const f16x8*)trow;
                f16x8 t1 = *(const f16x8*)(trow + 8);
                float acc = 0.f;
#pragma unroll
                for (int tp = 0; tp < 16; tp++) {
                    if (tp < sp) acc += (float)(tp < 8 ? t0[tp] : t1[tp - 8]) * Xs[a * 16 + tp];
                }
                Xs[a * 16 + sp] -= acc;
            }
        }
        if (wv < 2) {
#pragma unroll
            for (int v = 0; v < 8; v++) {
                f16x8 hv;
#pragma unroll
                for (int j = 0; j < 8; j++) hv[j] = (_Float16)Xs[v * 8 + j];
                *(f16x8*)&WTw[((long)hc * 128 + jcol) * 64 + v * 8] = hv;
            }
        } else {
#pragma unroll
            for (int t = 0; t < 64; t++) Bw[(long)hc * 8192 + t * 128 + jcol] = (_Float16)Xs[t];
#pragma unroll
            for (int v = 0; v < 8; v++) {
                f16x8 hv;
#pragma unroll
                for (int j = 0; j < 8; j++) hv[j] = (_Float16)Xs[v * 8 + j];
                *(f16x8*)&BTw[((long)hc * 128 + jcol) * 64 + v * 8] = hv;
            }
        }
    } else {
        const int w = wv - 4;
        // QT: rows w*16..w*16+15, scaled by egQ[t]
#pragma unroll
        for (int cp = 0; cp < 4; cp++) {
            int t = w * 16 + fr;
            int cc = cp * 32 + kof;
            f16x8 q = *(const f16x8*)&Qh[t * 136 + cc];
            float s = egQ[t];
            f16x8 o;
#pragma unroll
            for (int j = 0; j < 8; j++) o[j] = (_Float16)(s * (float)q[j]);
            *(f16x8*)&QTw[(long)hc * 8192 + t * 128 + cc] = o;
        }
        // KT: transposed Kh scaled by egKr[t]
        const int m = w * 32 + (lane & 31);
        const int tb = (lane >> 5) * 8;
#pragma unroll
        for (int tp = 0; tp < 4; tp++) {
            int t0 = tb + tp * 16;
            f16x8 o;
#pragma unroll
            for (int j = 0; j < 8; j++)
                o[j] = (_Float16)(egKr[t0 + j] * (float)Kh[(t0 + j) * 136 + m]);
            *(f16x8*)&KTw[(long)hc * 8192 + m * 64 + t0] = o;
        }
    }
}

// ---------------------------------------------------------------- G = K~^T B (f16), Rt = (K~^T W)^T (f32)
__global__ __launch_bounds__(256) void gr_kernel(const _Float16* __restrict__ KTw,
                                                 const _Float16* __restrict__ BTw,
                                                 const _Float16* __restrict__ WTw,
                                                 _Float16* __restrict__ Gw,
                                                 float* __restrict__ Rtw) {
    __shared__ _Float16 KTl[128 * 72], BTl[128 * 72], WTl[128 * 72];
    const long hc = blockIdx.x;
    const int tid = threadIdx.x;
    {
        int r = tid >> 1, c0 = (tid & 1) * 32;
        const _Float16* k_ = &KTw[hc * 8192 + r * 64 + c0];
        const _Float16* b_ = &BTw[hc * 8192 + r * 64 + c0];
        const _Float16* w_ = &WTw[hc * 8192 + r * 64 + c0];
#pragma unroll
        for (int i = 0; i < 4; i++) {
            *(f16x8*)&KTl[r * 72 + c0 + i * 8] = *(const f16x8*)&k_[i * 8];
            *(f16x8*)&BTl[r * 72 + c0 + i * 8] = *(const f16x8*)&b_[i * 8];
            *(f16x8*)&WTl[r * 72 + c0 + i * 8] = *(const f16x8*)&w_[i * 8];
        }
    }
    __syncthreads();
    const int wv = tid >> 6, lane = tid & 63;
    const int fr = lane & 15, kof = (lane >> 4) * 8, quad = lane >> 4;
    f32x4 zero = {0.f, 0.f, 0.f, 0.f};
#pragma unroll
    for (int mi = 0; mi < 2; mi++) {
        int m0 = (wv * 2 + mi) * 16;
        f16x8 a0 = *(const f16x8*)&KTl[(m0 + fr) * 72 + kof];
        f16x8 a1 = *(const f16x8*)&KTl[(m0 + fr) * 72 + 32 + kof];
#pragma unroll
        for (int nj = 0; nj < 8; nj++) {
            f32x4 acc = zero;
            acc = MFMA16(a0, *(const f16x8*)&BTl[(nj * 16 + fr) * 72 + kof], acc);
            acc = MFMA16(a1, *(const f16x8*)&BTl[(nj * 16 + fr) * 72 + 32 + kof], acc);
#pragma unroll
            for (int r = 0; r < 4; r++)
                Gw[hc * 16384 + (long)(m0 + quad * 4 + r) * 128 + nj * 16 + fr] = (_Float16)acc[r];
        }
    }
#pragma unroll
    for (int ji = 0; ji < 2; ji++) {
        int j0 = (wv * 2 + ji) * 16;
        f16x8 a0 = *(const f16x8*)&WTl[(j0 + fr) * 72 + kof];
        f16x8 a1 = *(const f16x8*)&WTl[(j0 + fr) * 72 + 32 + kof];
#pragma unroll
        for (int nm = 0; nm < 8; nm++) {
            f32x4 acc = zero;
            acc = MFMA16(a0, *(const f16x8*)&KTl[(nm * 16 + fr) * 72 + kof], acc);
            acc = MFMA16(a1, *(const f16x8*)&KTl[(nm * 16 + fr) * 72 + 32 + kof], acc);
#pragma unroll
            for (int r = 0; r < 4; r++)
                Rtw[hc * 16384 + (long)(j0 + quad * 4 + r) * 128 + nm * 16 + fr] = acc[r];
        }
    }
}

// ---------------------------------------------------------------- serial affine state scan
// Grid 128 = h(16) x js(8 of 16 rows); each block owns z[16][128].
__global__ __launch_bounds__(256) void serial_scan(const _Float16* __restrict__ Gw,
                                                   const float* __restrict__ Rtw,
                                                   const float* __restrict__ gamC,
                                                   float* __restrict__ Zdump) {
    __shared__ _Float16 Zhi[16 * 136], Zlo[16 * 136];
    __shared__ _Float16 Gl[128 * 136];
    const int tid = threadIdx.x;
    const int h = blockIdx.x >> 3, js = (blockIdx.x & 7) * 16;
    const int wv = tid >> 6, lane = tid & 63;
    const int fr = lane & 15, kof = (lane >> 4) * 8, quad = lane >> 4;
    const int gr_ = tid >> 1, gc_ = (tid & 1) * 64;

    for (int e = tid; e < 16 * 136; e += 256) { Zhi[e] = (_Float16)0.f; Zlo[e] = (_Float16)0.f; }
    float z[2][4];
#pragma unroll
    for (int u = 0; u < 2; u++)
#pragma unroll
        for (int r = 0; r < 4; r++) z[u][r] = 0.f;

    long hc0 = (long)h * 16;
    f16x8 gpre[8];
#pragma unroll
    for (int i = 0; i < 8; i++)
        gpre[i] = *(const f16x8*)&Gw[hc0 * 16384 + (long)gr_ * 128 + gc_ + i * 8];
    float rpre[2][4];
#pragma unroll
    for (int u = 0; u < 2; u++)
#pragma unroll
        for (int r = 0; r < 4; r++)
            rpre[u][r] = Rtw[hc0 * 16384 +
                             (long)(js + quad * 4 + r) * 128 + (2 * wv + u) * 16 + fr];
    __syncthreads();

    for (int c = 0; c < 16; ++c) {
        long hc = (long)h * 16 + c;
        float gC = gamC[hc];
#pragma unroll
        for (int i = 0; i < 8; i++)
            *(f16x8*)&Gl[gr_ * 136 + gc_ + i * 8] = gpre[i];
        long hcn = (long)h * 16 + (c < 15 ? c + 1 : 15);
        f16x8 gnext[8];
#pragma unroll
        for (int i = 0; i < 8; i++)
            gnext[i] = *(const f16x8*)&Gw[hcn * 16384 + (long)gr_ * 128 + gc_ + i * 8];
        float rnext[2][4];
#pragma unroll
        for (int u = 0; u < 2; u++)
#pragma unroll
            for (int r = 0; r < 4; r++)
                rnext[u][r] = Rtw[hcn * 16384 +
                                  (long)(js + quad * 4 + r) * 128 + (2 * wv + u) * 16 + fr];
        __syncthreads();
        f32x4 acc[2];
        f32x4 zero = {0.f, 0.f, 0.f, 0.f};
#pragma unroll
        for (int u = 0; u < 2; u++) acc[u] = zero;
        for (int k0 = 0; k0 < 128; k0 += 32) {
            f16x8 ahi = *(const f16x8*)&Zhi[fr * 136 + k0 + kof];
            f16x8 alo = *(const f16x8*)&Zlo[fr * 136 + k0 + kof];
#pragma unroll
            for (int u = 0; u < 2; u++) {
                f16x8 bfr = *(const f16x8*)&Gl[((2 * wv + u) * 16 + fr) * 136 + k0 + kof];
                acc[u] = MFMA16(ahi, bfr, acc[u]);
                acc[u] = MFMA16(alo, bfr, acc[u]);
            }
        }
        __syncthreads();
#pragma unroll
        for (int u = 0; u < 2; u++)
#pragma unroll
            for (int r = 0; r < 4; r++) {
                int j = quad * 4 + r;
                int m = (2 * wv + u) * 16 + fr;
                Zdump[hc * 16384 + (long)(js + j) * 128 + m] = z[u][r];
                float zn = gC * z[u][r] - acc[u][r] + rpre[u][r];
                z[u][r] = zn;
                _Float16 hi = (_Float16)zn;
                Zhi[j * 136 + m] = hi;
                Zlo[j * 136 + m] = (_Float16)(zn - (float)hi);
            }
#pragma unroll
        for (int i = 0; i < 8; i++) gpre[i] = gnext[i];
#pragma unroll
        for (int u = 0; u < 2; u++)
#pragma unroll
            for (int r = 0; r < 4; r++) rpre[u][r] = rnext[u][r];
    }
}

// ---------------------------------------------------------------- per-chunk output + RMS + gate, fused
// One block per hc, 512 threads (8 waves). Waves 0-3: column-half 0; waves 4-7: half 1.
__global__ __launch_bounds__(512) void out_fused(const float* __restrict__ Zdump,
                                                 const _Float16* __restrict__ Bw,
                                                 const _Float16* __restrict__ WTw,
                                                 const _Float16* __restrict__ QTw,
                                                 const _Float16* __restrict__ Mw,
                                                 const _Float16* __restrict__ pre,
                                                 const float* __restrict__ rms_w,
                                                 _Float16* __restrict__ y) {
    __shared__ _Float16 SThi[128 * 136], STlo[128 * 136];
    __shared__ _Float16 Bl[64 * 136];
    __shared__ _Float16 UT[2][64 * 72];
    __shared__ float rowsq[2][64];
    const long hc = blockIdx.x;
    const int h = (int)(hc >> 4), c = (int)(hc & 15), s0 = c * 64;
    const int tid = threadIdx.x, wv = tid >> 6, lane = tid & 63;
    const int half = wv >> 2, wvh = wv & 3, jh = half * 64;
    const int fr = lane & 15, kof = (lane >> 4) * 8, quad = lane >> 4;
    {
        int r = tid >> 2, c0 = (tid & 3) * 32;        // r: 0..127 dv rows
        const float* src = &Zdump[hc * 16384 + (long)r * 128 + c0];
#pragma unroll
        for (int i = 0; i < 8; i++) {
            float4 v = *(const float4*)&src[i * 4];
            _Float16 h0 = (_Float16)v.x, h1 = (_Float16)v.y, h2 = (_Float16)v.z, h3 = (_Float16)v.w;
            f16x4 hi = {h0, h1, h2, h3};
            f16x4 lo = {(_Float16)(v.x - (float)h0), (_Float16)(v.y - (float)h1),
                        (_Float16)(v.z - (float)h2), (_Float16)(v.w - (float)h3)};
            *(f16x4*)&SThi[r * 136 + c0 + i * 4] = hi;
            *(f16x4*)&STlo[r * 136 + c0 + i * 4] = lo;
        }
        if (tid < 256) {
            int r2 = tid >> 2, cb = (tid & 3) * 32;
            const _Float16* bsrc = &Bw[hc * 8192 + r2 * 128 + cb];
#pragma unroll
            for (int i = 0; i < 4; i++)
                *(f16x8*)&Bl[r2 * 136 + cb + i * 8] = *(const f16x8*)&bsrc[i * 8];
        }
    }
    __syncthreads();
    const int t0 = wvh * 16;
    f16x8 ba[4];
#pragma unroll
    for (int k = 0; k < 4; k++)
        ba[k] = *(const f16x8*)&Bl[(t0 + fr) * 136 + k * 32 + kof];
#pragma unroll
    for (int jt = 0; jt < 4; jt++) {
        f32x4 acc = {0.f, 0.f, 0.f, 0.f};
#pragma unroll
        for (int k = 0; k < 4; k++) {
            acc = MFMA16(ba[k], *(const f16x8*)&SThi[(jh + jt * 16 + fr) * 136 + k * 32 + kof], acc);
            acc = MFMA16(ba[k], *(const f16x8*)&STlo[(jh + jt * 16 + fr) * 136 + k * 32 + kof], acc);
        }
#pragma unroll
        for (int r = 0; r < 4; r++) {
            int t = t0 + quad * 4 + r;
            int j = jt * 16 + fr;
            float w = (float)WTw[hc * 8192 + (long)(jh + j) * 64 + t];
            UT[half][j * 72 + t] = (_Float16)(w - acc[r]);
        }
    }
    __syncthreads();
    f16x8 qa[4], ma[2];
#pragma unroll
    for (int k = 0; k < 4; k++)
        qa[k] = *(const f16x8*)&QTw[hc * 8192 + (long)(t0 + fr) * 128 + k * 32 + kof];
#pragma unroll
    for (int k = 0; k < 2; k++)
        ma[k] = *(const f16x8*)&Mw[hc * 4096 + (long)(t0 + fr) * 64 + k * 32 + kof];
    f32x4 out[4];
#pragma unroll
    for (int jt = 0; jt < 4; jt++) {
        f32x4 acc = {0.f, 0.f, 0.f, 0.f};
#pragma unroll
        for (int k = 0; k < 4; k++) {
            acc = MFMA16(qa[k], *(const f16x8*)&SThi[(jh + jt * 16 + fr) * 136 + k * 32 + kof], acc);
            acc = MFMA16(qa[k], *(const f16x8*)&STlo[(jh + jt * 16 + fr) * 136 + k * 32 + kof], acc);
        }
#pragma unroll
        for (int k = 0; k < 2; k++)
            acc = MFMA16(ma[k], *(const f16x8*)&UT[half][(jt * 16 + fr) * 72 + k * 32 + kof], acc);
        out[jt] = acc;
    }
    // ---- cross-half row RMS: partial sumsq over this half's 4 cols, reduce over fr
    float pr[4];
#pragma unroll
    for (int r = 0; r < 4; r++) {
        float s = 0.f;
#pragma unroll
        for (int jt = 0; jt < 4; jt++) s += out[jt][r] * out[jt][r];
        s += __shfl_xor(s, 1); s += __shfl_xor(s, 2);
        s += __shfl_xor(s, 4); s += __shfl_xor(s, 8);
        pr[r] = s;
    }
    if (fr == 0) {
#pragma unroll
        for (int r = 0; r < 4; r++) rowsq[half][t0 + quad * 4 + r] = pr[r];
    }
    __syncthreads();
#pragma unroll
    for (int r = 0; r < 4; r++) {
        int t = t0 + quad * 4 + r;
        float ss = rowsq[0][t] + rowsq[1][t];
        float sc = rsqrtf(ss * (1.f / 128.f) + 1e-6f);
        long rb = (long)(s0 + t) * 6144 + 4096 + h * 128 + jh;
        long yb_ = (long)(s0 + t) * 2048 + h * 128 + jh;
#pragma unroll
        for (int jt = 0; jt < 4; jt++) {
            int j = jt * 16 + fr;
            float g = silu_f((float)pre[rb + j]);
            y[yb_ + j] = (_Float16)(out[jt][r] * sc * rms_w[jh + j] * g);
        }
    }
}

// ---------------------------------------------------------------- launch
extern "C" void kernel_launch(void* const* d_in, const int* in_sizes, int n_in,
                              void* d_out, int out_size, void* d_ws, size_t ws_size,
                              hipStream_t stream) {
    const float* x       = (const float*)d_in[0];
    const float* w_qkv   = (const float*)d_in[1];
    const float* w_gate  = (const float*)d_in[2];
    const float* w_beta  = (const float*)d_in[3];
    const float* w_alpha = (const float*)d_in[4];
    const float* log_A   = (const float*)d_in[5];
    const float* dt_bias = (const float*)d_in[6];
    const float* conv_w  = (const float*)d_in[7];
    const float* rms_w   = (const float*)d_in[8];
    const float* w_out   = (const float*)d_in[9];
    float* outp = (float*)d_out;

    char* ws = (char*)d_ws;
    size_t off = 0;
    _Float16* xb     = (_Float16*)(ws + off); off += (size_t)1024 * 2048 * 2;   // | contiguous
    _Float16* wfused = (_Float16*)(ws + off); off += (size_t)6144 * 2048 * 2;   // | f16 cvt
    _Float16* woutb  = (_Float16*)(ws + off); off += (size_t)2048 * 2048 * 2;   // | region
    _Float16* yb     = (_Float16*)(ws + off); off += (size_t)1024 * 2048 * 2;
    _Float16* pre    = (_Float16*)(ws + off); off += (size_t)1024 * 6144 * 2;
    float* betaB     = (float*)(ws + off);    off += (size_t)1024 * 16 * 4;
    float* lalphaB   = (float*)(ws + off);    off += (size_t)1024 * 16 * 4;
    _Float16* Mw     = (_Float16*)(ws + off); off += (size_t)256 * 4096 * 2;
    _Float16* QTw    = (_Float16*)(ws + off); off += (size_t)256 * 8192 * 2;
    _Float16* KTw    = (_Float16*)(ws + off); off += (size_t)256 * 8192 * 2;
    _Float16* WTw    = (_Float16*)(ws + off); off += (size_t)256 * 8192 * 2;
    _Float16* Bw     = (_Float16*)(ws + off); off += (size_t)256 * 8192 * 2;
    _Float16* BTw    = (_Float16*)(ws + off); off += (size_t)256 * 8192 * 2;
    float* gamC      = (float*)(ws + off);    off += (size_t)256 * 4;
    _Float16* Gw     = (_Float16*)(ws + off); off += (size_t)256 * 16384 * 2;
    float* Rtw       = (float*)(ws + off);    off += (size_t)256 * 16384 * 4;
    float* Zdump     = (float*)(ws + off);    off += (size_t)256 * 16384 * 4;

    // all f32->f16 conversions (8 float4/thread) + beta/alpha projections, one launch
    cvt_proj<<<3328, 256, 0, stream>>>(x, w_qkv, w_gate, w_out, xb,
                                       w_beta, w_alpha, log_A, dt_bias, betaB, lalphaB);

    // fused qkv+gate projection: 128x128 tiles + XCD-aware swizzle
    gemm_bt128h<<<dim3(48, 8), 256, 0, stream>>>(xb, wfused, pre, 6144, 2048);

    // conv+norm+prep+solve fused: one block per (head,chunk), 8 waves
    chunk_front<<<256, 512, 0, stream>>>(pre, conv_w, betaB, lalphaB,
                                         Mw, QTw, KTw, WTw, Bw, BTw, gamC);
    gr_kernel<<<256, 256, 0, stream>>>(KTw, BTw, WTw, Gw, Rtw);
    serial_scan<<<128, 256, 0, stream>>>(Gw, Rtw, gamC, Zdump);

    // per-chunk output + RMS + gate fused: one block per hc, 8 waves
    out_fused<<<256, 512, 0, stream>>>(Zdump, Bw, WTw, QTw, Mw, pre, rms_w, yb);

    // out projection: 64x64 tiles + XCD-aware swizzle
    gemm_bt6464<<<dim3(32, 16), 256, 0, stream>>>(yb, woutb, outp, 2048, 2048);
}